// Round 19
// baseline (419.744 us; speedup 1.0000x reference)
//
#include <hip/hip_runtime.h>
#include <hip/hip_bf16.h>

#define SEQ 2048

typedef __attribute__((ext_vector_type(8))) short short8;
typedef __attribute__((ext_vector_type(4))) float f32x4;

__device__ __forceinline__ unsigned short f2bf(float f) {
  unsigned u = __float_as_uint(f);
  u += 0x7fffu + ((u >> 16) & 1u);
  return (unsigned short)(u >> 16);
}

// Pack two f32 -> bf16x2 via the COMPILER-VISIBLE HIP conversion (no inline asm).
// R13-R16 lesson: v_exp_f32 is a TRANS op with a result-use wait-state; the hazard
// recognizer does NOT pad when the consumer is an opaque inline-asm block. Keeping
// producer (builtin exp2) AND consumer visible lets the compiler manage the hazard.
__device__ __forceinline__ unsigned pack_bf16x2(float lo, float hi) {
  __hip_bfloat162 h = __float22bfloat162_rn(float2{lo, hi});
  unsigned r;
  __builtin_memcpy(&r, &h, 4);
  return r;
}

// tanh-form GELU: x * sigmoid(1.5957691*x*(1+0.044715*x^2)). Max |err| vs erf-GELU ~3e-4.
__device__ __forceinline__ float gelu_fast(float x) {
  const float u = 1.5957691f * x * __builtin_fmaf(0.044715f, x * x, 1.0f);
  const float e = __builtin_amdgcn_exp2f(-1.4426950408889634f * u);  // exp(-u)
  return x * __builtin_amdgcn_rcpf(1.0f + e);
}

__device__ __forceinline__ void async_ld16(const unsigned short* g, unsigned short* l) {
  __builtin_amdgcn_global_load_lds((const __attribute__((address_space(1))) unsigned int*)g,
                                   (__attribute__((address_space(3))) unsigned int*)l, 16, 0, 0);
}

// ---------------- 128x128 GEMM (verified m97-class) + T1 XCD swizzle ----------------
// EPI 0: bf16 store; EPI 1: gelu+bf16 store (tanh-form); EPI 2: fp32 store;
// EPI 3: bf16 store with Q-scale fold (cols<1024 × log2(e)/8) for the QKV GEMM.
// 1D grid, bijective XCD remap (m204: valid since nwg%8==0 for all four shapes), decoded
// by-fastest so each XCD pins 1-4 B column-panels in its private L2 while A streams
// (R18: FF1 FETCH 82MB vs 24MB ideal = panel thrash under default round-robin dispatch).
// M is fixed at 8192 -> 64 row-tiles (by = lin & 63).
template<int EPI>
__global__ __launch_bounds__(256)
void gemm_bf16(const unsigned short* __restrict__ A,
               const unsigned short* __restrict__ Bt,
               const float* __restrict__ bias,
               void* __restrict__ Cout,
               int M, int N, int K) {
  __shared__ alignas(16) unsigned short As[128 * 64];
  __shared__ alignas(16) unsigned short Bs[128 * 64];
  const int tid = threadIdx.x;
  const int lane = tid & 63;
  const int wid = tid >> 6;
  const int wr = wid >> 1, wc = wid & 1;

  // T1: XCD-chunked bijective remap of the linear block id, by-fastest decode.
  const int nwg = gridDim.x;
  const int lin = (blockIdx.x & 7) * (nwg >> 3) + (blockIdx.x >> 3);
  const int by = lin & 63;        // M/128 == 64 (M fixed at 8192)
  const int bx = lin >> 6;
  const int rowbase = by * 128;
  const int colbase = bx * 128;
  const int g = lane >> 4, c = lane & 15;

  f32x4 acc[4][4];
#pragma unroll
  for (int m = 0; m < 4; m++)
#pragma unroll
    for (int n = 0; n < 4; n++) acc[m][n] = f32x4{0.f, 0.f, 0.f, 0.f};

  const int lrow = lane >> 3;
  const int swzel = (((lane & 7) ^ lrow) << 3);
  const unsigned short* gA = A + (size_t)(rowbase + wid * 32 + lrow) * K + swzel;
  const unsigned short* gB = Bt + (size_t)(colbase + wid * 32 + lrow) * K + swzel;
  unsigned short* lA = As + wid * 2048;
  unsigned short* lB = Bs + wid * 2048;

  for (int kt = 0; kt < K; kt += 64) {
#pragma unroll
    for (int i = 0; i < 4; i++) async_ld16(gA + kt + (size_t)i * 8 * K, lA + i * 512);
#pragma unroll
    for (int i = 0; i < 4; i++) async_ld16(gB + kt + (size_t)i * 8 * K, lB + i * 512);
    __syncthreads();
#pragma unroll
    for (int kb = 0; kb < 2; ++kb) {
      short8 av[4], bv[4];
#pragma unroll
      for (int m = 0; m < 4; m++) {
        const int row = wr * 64 + m * 16 + c;
        const int cb = (kb * 64 + g * 16) ^ ((row & 7) << 4);
        av[m] = *(const short8*)((const char*)As + row * 128 + cb);
      }
#pragma unroll
      for (int n = 0; n < 4; n++) {
        const int row = wc * 64 + n * 16 + c;
        const int cb = (kb * 64 + g * 16) ^ ((row & 7) << 4);
        bv[n] = *(const short8*)((const char*)Bs + row * 128 + cb);
      }
#pragma unroll
      for (int m = 0; m < 4; m++)
#pragma unroll
        for (int n = 0; n < 4; n++)
          acc[m][n] = __builtin_amdgcn_mfma_f32_16x16x32_bf16(av[m], bv[n], acc[m][n], 0, 0, 0);
    }
    __syncthreads();
  }

#pragma unroll
  for (int m = 0; m < 4; m++) {
    const int row0 = rowbase + wr * 64 + m * 16 + g * 4;
#pragma unroll
    for (int n = 0; n < 4; n++) {
      const int col = colbase + wc * 64 + n * 16 + c;
      const float bb = bias[col];
#pragma unroll
      for (int r = 0; r < 4; r++) {
        float v = acc[m][n][r] + bb;
        const size_t idx = (size_t)(row0 + r) * N + col;
        if (EPI == 1) {
          v = gelu_fast(v);
          ((unsigned short*)Cout)[idx] = f2bf(v);
        } else if (EPI == 2) {
          ((float*)Cout)[idx] = v;
        } else if (EPI == 3) {
          v = (col < 1024) ? v * 0.18033688f : v;  // fold (1/sqrt(64))*log2(e) into Q
          ((unsigned short*)Cout)[idx] = f2bf(v);
        } else {
          ((unsigned short*)Cout)[idx] = f2bf(v);
        }
      }
    }
  }
}

// ---------------- weight transpose-convert: W fp32 [K][N] -> Wt bf16 [N][K] ----------------
__global__ __launch_bounds__(256)
void wtrans(const float* __restrict__ W, unsigned short* __restrict__ Wt, int K, int N) {
  __shared__ unsigned short tile[64][72];
  const int n0 = blockIdx.x * 64, k0 = blockIdx.y * 64;
  const int t = threadIdx.x;
  {
    const int kl = t >> 2, nl0 = (t & 3) * 16;
    const float4* src = (const float4*)(W + (size_t)(k0 + kl) * N + n0 + nl0);
#pragma unroll
    for (int i = 0; i < 4; i++) {
      float4 v = src[i];
      tile[kl][nl0 + i * 4 + 0] = f2bf(v.x);
      tile[kl][nl0 + i * 4 + 1] = f2bf(v.y);
      tile[kl][nl0 + i * 4 + 2] = f2bf(v.z);
      tile[kl][nl0 + i * 4 + 3] = f2bf(v.w);
    }
  }
  __syncthreads();
  {
    const int nl = t >> 2, kl0 = (t & 3) * 16;
    unsigned short* dst = Wt + (size_t)(n0 + nl) * K + k0 + kl0;
    short8 a, b2;
#pragma unroll
    for (int j = 0; j < 8; j++) {
      a[j]  = (short)tile[kl0 + j][nl];
      b2[j] = (short)tile[kl0 + 8 + j][nl];
    }
    *(short8*)dst = a;
    *(short8*)(dst + 8) = b2;
  }
}

// ---------------- V transpose: qkv V-part [b][s][h][dh] -> Vt [b*h][dh][s] ----------------
__global__ __launch_bounds__(256)
void vtrans(const unsigned short* __restrict__ qkv, unsigned short* __restrict__ Vt) {
  __shared__ unsigned short tile[64][72];
  const int blk = blockIdx.x;
  const int st = blk & 31, bh = blk >> 5;
  const int b = bh >> 4, h = bh & 15;
  const int s0 = st * 64;
  const int t = threadIdx.x;
  {
    const int sl = t >> 2, d0 = (t & 3) * 16;
    const unsigned short* src = qkv + (size_t)(b * SEQ + s0 + sl) * 3072 + 2048 + h * 64 + d0;
    short8 v0 = *(const short8*)src;
    short8 v1 = *(const short8*)(src + 8);
#pragma unroll
    for (int j = 0; j < 8; j++) {
      tile[sl][d0 + j] = (unsigned short)v0[j];
      tile[sl][d0 + 8 + j] = (unsigned short)v1[j];
    }
  }
  __syncthreads();
  {
    const int dl = t >> 2, sl0 = (t & 3) * 16;
    unsigned short* dst = Vt + ((size_t)bh * 64 + dl) * SEQ + s0 + sl0;
    short8 a, b2;
#pragma unroll
    for (int j = 0; j < 8; j++) {
      a[j]  = (short)tile[sl0 + j][dl];
      b2[j] = (short)tile[sl0 + 8 + j][dl];
    }
    *(short8*)dst = a;
    *(short8*)(dst + 8) = b2;
  }
}

// ---------------- RMSNorm: fp32 in -> bf16 out, one row per block ----------------
__global__ __launch_bounds__(256)
void rmsnorm_f32_bf16(const float* __restrict__ x, const float* __restrict__ w,
                      unsigned short* __restrict__ out) {
  __shared__ float red[4];
  const int row = blockIdx.x, t = threadIdx.x;
  const float4 v = ((const float4*)(x + (size_t)row * 1024))[t];
  float ss = v.x * v.x + v.y * v.y + v.z * v.z + v.w * v.w;
#pragma unroll
  for (int d = 1; d < 64; d <<= 1) ss += __shfl_xor(ss, d);
  if ((t & 63) == 0) red[t >> 6] = ss;
  __syncthreads();
  const float tot = red[0] + red[1] + red[2] + red[3];
  const float r = rsqrtf(tot * (1.0f / 1024.0f) + 1e-6f);
  const float4 wv = ((const float4*)w)[t];
  ushort4 o;
  o.x = f2bf(v.x * r * wv.x);
  o.y = f2bf(v.y * r * wv.y);
  o.z = f2bf(v.z * r * wv.z);
  o.w = f2bf(v.w * r * wv.w);
  *((ushort4*)(out + (size_t)row * 1024 + t * 4)) = o;
}

// ---------------- flash attention: 8 waves x 32 q-rows, kb2-split + s_setprio (T5) --------
// Structure: R12/R16/R18 winner (kb2-split softmax||PV, compile-time buf, constant m=0,
// l via ones-MFMA, K+V LDS dbuf via global_load_lds, both-sides XOR swizzle, visible
// exp2+pack, setprio around MFMA clusters).
__global__ __launch_bounds__(512, 4)
void attn(const unsigned short* __restrict__ qkv, const unsigned short* __restrict__ Vt,
          unsigned short* __restrict__ ctx) {
  __shared__ alignas(16) unsigned short Ks[2][64 * 64];
  __shared__ alignas(16) unsigned short Vs[2][64 * 64];
  __shared__ alignas(16) unsigned short Plds[8][32 * 72];
  const int tid = threadIdx.x, lane = tid & 63, wid = tid >> 6;
  const int qb = blockIdx.x & 7, bh = blockIdx.x >> 3;
  const int b = bh >> 4, h = bh & 15;
  const int g = lane >> 4, c = lane & 15;
  const int qrow0 = qb * 256 + wid * 32;

  const unsigned short* Kb = qkv + (size_t)b * SEQ * 3072 + 1024 + h * 64;
  const unsigned short* Vb = Vt + (size_t)bh * 64 * SEQ;

  const int srow = lane >> 3;
  const int swz = (((lane & 7) ^ srow) << 3);

  short8 bq[2][2];
#pragma unroll
  for (int m = 0; m < 2; m++)
#pragma unroll
    for (int kb = 0; kb < 2; kb++) {
      const int sq = qrow0 + m * 16 + c;
      bq[m][kb] = *(const short8*)(qkv + (size_t)(b * SEQ + sq) * 3072 + h * 64 + kb * 32 + g * 8);
    }

  short8 ones;
#pragma unroll
  for (int j = 0; j < 8; j++) ones[j] = (short)0x3F80;

  f32x4 o[2][4];
  f32x4 lacc[2];
#pragma unroll
  for (int m = 0; m < 2; m++) {
#pragma unroll
    for (int nc = 0; nc < 4; nc++) o[m][nc] = f32x4{0.f, 0.f, 0.f, 0.f};
    lacc[m] = f32x4{0.f, 0.f, 0.f, 0.f};
  }

  unsigned short* pw = &Plds[wid][0];

  async_ld16(Kb + (size_t)(wid * 8 + srow) * 3072 + swz, &Ks[0][wid * 512]);
  async_ld16(Vb + (size_t)(wid * 8 + srow) * 2048 + swz, &Vs[0][wid * 512]);
  __syncthreads();

  for (int tt = 0; tt < SEQ / 128; ++tt) {
#pragma unroll
    for (int half = 0; half < 2; ++half) {
      const int t = tt * 2 + half;                  // buf == half (compile-time)
      const char* ksb = (const char*)Ks + half * 8192;
      const char* vsb = (const char*)Vs + half * 8192;
      if (t + 1 < SEQ / 64) {
        const int kt2 = (t + 1) * 64;
        async_ld16(Kb + (size_t)(kt2 + wid * 8 + srow) * 3072 + swz, &Ks[half ^ 1][wid * 512]);
        async_ld16(Vb + (size_t)(wid * 8 + srow) * 2048 + kt2 + swz, &Vs[half ^ 1][wid * 512]);
      }

      // QK: sacc[m][n] reg r = (pre-scaled) S^T[k = n*16+g*4+r][q = m*16+c]
      f32x4 sacc[2][4];
#pragma unroll
      for (int m = 0; m < 2; m++)
#pragma unroll
        for (int n = 0; n < 4; n++) sacc[m][n] = f32x4{0.f, 0.f, 0.f, 0.f};
#pragma unroll
      for (int kb = 0; kb < 2; ++kb) {
        short8 ak[4];
#pragma unroll
        for (int n = 0; n < 4; n++)
          ak[n] = *(const short8*)(ksb + (n * 16 + c) * 128 +
                                   ((kb * 64 + g * 16) ^ ((c & 7) << 4)));
        __builtin_amdgcn_s_setprio(1);
#pragma unroll
        for (int m = 0; m < 2; m++)
#pragma unroll
          for (int n = 0; n < 4; n++)
            sacc[m][n] = __builtin_amdgcn_mfma_f32_16x16x32_bf16(ak[n], bq[m][kb], sacc[m][n], 0, 0, 0);
        __builtin_amdgcn_s_setprio(0);
      }

      // per 32-k half: exp+pack (n = 2*kb2, 2*kb2+1) -> pa -> PV half; PV MFMA of half 0
      // overlaps the exp chain of half 1.
#pragma unroll
      for (int kb2 = 0; kb2 < 2; ++kb2) {
#pragma unroll
        for (int m = 0; m < 2; m++) {
          char* rowp = (char*)pw + (m * 16 + c) * 144;
#pragma unroll
          for (int nn = 0; nn < 2; nn++) {
            const int n = kb2 * 2 + nn;
            const float p0 = __builtin_amdgcn_exp2f(sacc[m][n][0]);
            const float p1 = __builtin_amdgcn_exp2f(sacc[m][n][1]);
            const float p2 = __builtin_amdgcn_exp2f(sacc[m][n][2]);
            const float p3 = __builtin_amdgcn_exp2f(sacc[m][n][3]);
            *(unsigned*)(rowp + (n * 16 + g * 4) * 2)     = pack_bf16x2(p0, p1);
            *(unsigned*)(rowp + (n * 16 + g * 4) * 2 + 4) = pack_bf16x2(p2, p3);
          }
        }
        short8 pa[2];
#pragma unroll
        for (int m = 0; m < 2; m++)
          pa[m] = *(const short8*)((const char*)pw + (m * 16 + c) * 144 + kb2 * 64 + g * 16);
        __builtin_amdgcn_s_setprio(1);
#pragma unroll
        for (int nc = 0; nc < 4; nc++) {
          const short8 vb = *(const short8*)(vsb + (nc * 16 + c) * 128 +
                                             ((kb2 * 64 + g * 16) ^ ((c & 7) << 4)));
#pragma unroll
          for (int m = 0; m < 2; m++)
            o[m][nc] = __builtin_amdgcn_mfma_f32_16x16x32_bf16(pa[m], vb, o[m][nc], 0, 0, 0);
        }
#pragma unroll
        for (int m = 0; m < 2; m++)
          lacc[m] = __builtin_amdgcn_mfma_f32_16x16x32_bf16(pa[m], ones, lacc[m], 0, 0, 0);
        __builtin_amdgcn_s_setprio(0);
      }
      __syncthreads();
    }
  }

  // epilogue: lacc[m][r] = l[q = m*16+g*4+r] — same row mapping as o[m][nc][r]; no shuffles
#pragma unroll
  for (int m = 0; m < 2; m++)
#pragma unroll
    for (int r = 0; r < 4; r++) {
      const float linv = 1.0f / lacc[m][r];
      const int sq = qrow0 + m * 16 + g * 4 + r;
#pragma unroll
      for (int nc = 0; nc < 4; nc++) {
        const int d = h * 64 + nc * 16 + c;
        ctx[(size_t)(b * SEQ + sq) * 1024 + d] = f2bf(o[m][nc][r] * linv);
      }
    }
}

extern "C" void kernel_launch(void* const* d_in, const int* in_sizes, int n_in,
                              void* d_out, int out_size, void* d_ws, size_t ws_size,
                              hipStream_t stream) {
  const float* x     = (const float*)d_in[0];
  const float* W_qkv = (const float*)d_in[1];
  const float* b_qkv = (const float*)d_in[2];
  const float* W_o   = (const float*)d_in[3];
  const float* b_o   = (const float*)d_in[4];
  const float* W_ff1 = (const float*)d_in[5];
  const float* b_ff1 = (const float*)d_in[6];
  const float* W_ff2 = (const float*)d_in[7];
  const float* b_ff2 = (const float*)d_in[8];
  const float* n1    = (const float*)d_in[9];
  const float* n2    = (const float*)d_in[10];
  float* out = (float*)d_out;

  char* p = (char*)d_ws;
  unsigned short* Wt_qkv = (unsigned short*)p; p += (size_t)3072 * 1024 * 2;
  unsigned short* Wt_o   = (unsigned short*)p; p += (size_t)1024 * 1024 * 2;
  unsigned short* Wt_ff1 = (unsigned short*)p; p += (size_t)4096 * 1024 * 2;
  unsigned short* Wt_ff2 = (unsigned short*)p; p += (size_t)1024 * 4096 * 2;
  unsigned short* xn  = (unsigned short*)p; p += (size_t)8192 * 1024 * 2;  // reused as ctx
  unsigned short* qkv = (unsigned short*)p; p += (size_t)8192 * 3072 * 2;  // reused as attn_out(fp32)
  unsigned short* Vt  = (unsigned short*)p; p += (size_t)8192 * 1024 * 2;  // reused as yn
  unsigned short* h   = (unsigned short*)p; p += (size_t)8192 * 4096 * 2;

  unsigned short* ctxb = xn;
  float* attn_out = (float*)qkv;
  unsigned short* yn = Vt;

  wtrans<<<dim3(48, 16), 256, 0, stream>>>(W_qkv, Wt_qkv, 1024, 3072);
  wtrans<<<dim3(16, 16), 256, 0, stream>>>(W_o,   Wt_o,   1024, 1024);
  wtrans<<<dim3(64, 16), 256, 0, stream>>>(W_ff1, Wt_ff1, 1024, 4096);
  wtrans<<<dim3(16, 64), 256, 0, stream>>>(W_ff2, Wt_ff2, 4096, 1024);

  rmsnorm_f32_bf16<<<8192, 256, 0, stream>>>(x, n1, xn);
  gemm_bf16<3><<<24 * 64, 256, 0, stream>>>(xn, Wt_qkv, b_qkv, (void*)qkv, 8192, 3072, 1024);
  vtrans<<<2048, 256, 0, stream>>>(qkv, Vt);
  attn<<<512, 512, 0, stream>>>(qkv, Vt, ctxb);
  gemm_bf16<2><<<8 * 64, 256, 0, stream>>>(ctxb, Wt_o, b_o, (void*)attn_out, 8192, 1024, 1024);
  rmsnorm_f32_bf16<<<8192, 256, 0, stream>>>(attn_out, n2, yn);
  gemm_bf16<1><<<32 * 64, 256, 0, stream>>>(yn, Wt_ff1, b_ff1, (void*)h, 8192, 4096, 1024);
  gemm_bf16<2><<<8 * 64, 256, 0, stream>>>(h, Wt_ff2, b_ff2, (void*)out, 8192, 1024, 4096);
}

// Round 20
// 381.247 us; speedup vs baseline: 1.1010x; 1.1010x over previous
//
#include <hip/hip_runtime.h>
#include <hip/hip_bf16.h>

#define SEQ 2048

typedef __attribute__((ext_vector_type(8))) short short8;
typedef __attribute__((ext_vector_type(4))) float f32x4;

__device__ __forceinline__ unsigned short f2bf(float f) {
  unsigned u = __float_as_uint(f);
  u += 0x7fffu + ((u >> 16) & 1u);
  return (unsigned short)(u >> 16);
}

// Pack two f32 -> bf16x2 via the COMPILER-VISIBLE HIP conversion (no inline asm).
// R13-R16 lesson: v_exp_f32 is a TRANS op with a result-use wait-state; the hazard
// recognizer does NOT pad when the consumer is an opaque inline-asm block.
__device__ __forceinline__ unsigned pack_bf16x2(float lo, float hi) {
  __hip_bfloat162 h = __float22bfloat162_rn(float2{lo, hi});
  unsigned r;
  __builtin_memcpy(&r, &h, 4);
  return r;
}

// tanh-form GELU: x * sigmoid(1.5957691*x*(1+0.044715*x^2)). Max |err| vs erf-GELU ~3e-4.
__device__ __forceinline__ float gelu_fast(float x) {
  const float u = 1.5957691f * x * __builtin_fmaf(0.044715f, x * x, 1.0f);
  const float e = __builtin_amdgcn_exp2f(-1.4426950408889634f * u);  // exp(-u)
  return x * __builtin_amdgcn_rcpf(1.0f + e);
}

__device__ __forceinline__ void async_ld16(const unsigned short* g, unsigned short* l) {
  __builtin_amdgcn_global_load_lds((const __attribute__((address_space(1))) unsigned int*)g,
                                   (__attribute__((address_space(3))) unsigned int*)l, 16, 0, 0);
}

// ---------------- 128x128 GEMM (verified m97-class) + T1 supertile XCD swizzle ------------
// R19 postmortem: by-fastest decode thrashed A (FETCH 82->266MB — each XCD's in-flight
// window spanned all 64 row-tiles). Footprint arithmetic: 64 in-flight blocks/XCD need
// by_win*256K + bx_win*256K <= 4MB L2 -> compact 8x4 SUPERTILES (32 blocks, 2MB A + 1MB B).
// Decode: XCD-chunked lin -> supertile (row-group-major so consecutive supertiles share
// A-rows) -> 8x4 interior. Bijective: NBX%4==0 and CHUNK%32==0 for all four shapes.
template<int EPI>
__global__ __launch_bounds__(256)
void gemm_bf16(const unsigned short* __restrict__ A,
               const unsigned short* __restrict__ Bt,
               const float* __restrict__ bias,
               void* __restrict__ Cout,
               int M, int N, int K) {
  __shared__ alignas(16) unsigned short As[128 * 64];
  __shared__ alignas(16) unsigned short Bs[128 * 64];
  const int tid = threadIdx.x;
  const int lane = tid & 63;
  const int wid = tid >> 6;
  const int wr = wid >> 1, wc = wid & 1;

  // T1: XCD-chunked bijective remap, supertile decode.
  const int nwg = gridDim.x;
  const int lin = (blockIdx.x & 7) * (nwg >> 3) + (blockIdx.x >> 3);
  const int nstx = N >> 9;              // (N/128)/4 supertile columns
  const int st = lin >> 5;              // 32 blocks per 8x4 supertile
  const int i = lin & 31;
  const int byg = st / nstx;            // 0..7 (row-group-major: A-rows shared per XCD)
  const int bxg = st - byg * nstx;
  const int rowbase = (byg * 8 + (i >> 2)) * 128;
  const int colbase = (bxg * 4 + (i & 3)) * 128;
  const int g = lane >> 4, c = lane & 15;

  f32x4 acc[4][4];
#pragma unroll
  for (int m = 0; m < 4; m++)
#pragma unroll
    for (int n = 0; n < 4; n++) acc[m][n] = f32x4{0.f, 0.f, 0.f, 0.f};

  const int lrow = lane >> 3;
  const int swzel = (((lane & 7) ^ lrow) << 3);
  const unsigned short* gA = A + (size_t)(rowbase + wid * 32 + lrow) * K + swzel;
  const unsigned short* gB = Bt + (size_t)(colbase + wid * 32 + lrow) * K + swzel;
  unsigned short* lA = As + wid * 2048;
  unsigned short* lB = Bs + wid * 2048;

  for (int kt = 0; kt < K; kt += 64) {
#pragma unroll
    for (int i2 = 0; i2 < 4; i2++) async_ld16(gA + kt + (size_t)i2 * 8 * K, lA + i2 * 512);
#pragma unroll
    for (int i2 = 0; i2 < 4; i2++) async_ld16(gB + kt + (size_t)i2 * 8 * K, lB + i2 * 512);
    __syncthreads();
#pragma unroll
    for (int kb = 0; kb < 2; ++kb) {
      short8 av[4], bv[4];
#pragma unroll
      for (int m = 0; m < 4; m++) {
        const int row = wr * 64 + m * 16 + c;
        const int cb = (kb * 64 + g * 16) ^ ((row & 7) << 4);
        av[m] = *(const short8*)((const char*)As + row * 128 + cb);
      }
#pragma unroll
      for (int n = 0; n < 4; n++) {
        const int row = wc * 64 + n * 16 + c;
        const int cb = (kb * 64 + g * 16) ^ ((row & 7) << 4);
        bv[n] = *(const short8*)((const char*)Bs + row * 128 + cb);
      }
#pragma unroll
      for (int m = 0; m < 4; m++)
#pragma unroll
        for (int n = 0; n < 4; n++)
          acc[m][n] = __builtin_amdgcn_mfma_f32_16x16x32_bf16(av[m], bv[n], acc[m][n], 0, 0, 0);
    }
    __syncthreads();
  }

#pragma unroll
  for (int m = 0; m < 4; m++) {
    const int row0 = rowbase + wr * 64 + m * 16 + g * 4;
#pragma unroll
    for (int n = 0; n < 4; n++) {
      const int col = colbase + wc * 64 + n * 16 + c;
      const float bb = bias[col];
#pragma unroll
      for (int r = 0; r < 4; r++) {
        float v = acc[m][n][r] + bb;
        const size_t idx = (size_t)(row0 + r) * N + col;
        if (EPI == 1) {
          v = gelu_fast(v);
          ((unsigned short*)Cout)[idx] = f2bf(v);
        } else if (EPI == 2) {
          ((float*)Cout)[idx] = v;
        } else if (EPI == 3) {
          v = (col < 1024) ? v * 0.18033688f : v;  // fold (1/sqrt(64))*log2(e) into Q
          ((unsigned short*)Cout)[idx] = f2bf(v);
        } else {
          ((unsigned short*)Cout)[idx] = f2bf(v);
        }
      }
    }
  }
}

// ---------------- weight transpose-convert: W fp32 [K][N] -> Wt bf16 [N][K] ----------------
__global__ __launch_bounds__(256)
void wtrans(const float* __restrict__ W, unsigned short* __restrict__ Wt, int K, int N) {
  __shared__ unsigned short tile[64][72];
  const int n0 = blockIdx.x * 64, k0 = blockIdx.y * 64;
  const int t = threadIdx.x;
  {
    const int kl = t >> 2, nl0 = (t & 3) * 16;
    const float4* src = (const float4*)(W + (size_t)(k0 + kl) * N + n0 + nl0);
#pragma unroll
    for (int i = 0; i < 4; i++) {
      float4 v = src[i];
      tile[kl][nl0 + i * 4 + 0] = f2bf(v.x);
      tile[kl][nl0 + i * 4 + 1] = f2bf(v.y);
      tile[kl][nl0 + i * 4 + 2] = f2bf(v.z);
      tile[kl][nl0 + i * 4 + 3] = f2bf(v.w);
    }
  }
  __syncthreads();
  {
    const int nl = t >> 2, kl0 = (t & 3) * 16;
    unsigned short* dst = Wt + (size_t)(n0 + nl) * K + k0 + kl0;
    short8 a, b2;
#pragma unroll
    for (int j = 0; j < 8; j++) {
      a[j]  = (short)tile[kl0 + j][nl];
      b2[j] = (short)tile[kl0 + 8 + j][nl];
    }
    *(short8*)dst = a;
    *(short8*)(dst + 8) = b2;
  }
}

// ---------------- V transpose: qkv V-part [b][s][h][dh] -> Vt [b*h][dh][s] ----------------
__global__ __launch_bounds__(256)
void vtrans(const unsigned short* __restrict__ qkv, unsigned short* __restrict__ Vt) {
  __shared__ unsigned short tile[64][72];
  const int blk = blockIdx.x;
  const int st = blk & 31, bh = blk >> 5;
  const int b = bh >> 4, h = bh & 15;
  const int s0 = st * 64;
  const int t = threadIdx.x;
  {
    const int sl = t >> 2, d0 = (t & 3) * 16;
    const unsigned short* src = qkv + (size_t)(b * SEQ + s0 + sl) * 3072 + 2048 + h * 64 + d0;
    short8 v0 = *(const short8*)src;
    short8 v1 = *(const short8*)(src + 8);
#pragma unroll
    for (int j = 0; j < 8; j++) {
      tile[sl][d0 + j] = (unsigned short)v0[j];
      tile[sl][d0 + 8 + j] = (unsigned short)v1[j];
    }
  }
  __syncthreads();
  {
    const int dl = t >> 2, sl0 = (t & 3) * 16;
    unsigned short* dst = Vt + ((size_t)bh * 64 + dl) * SEQ + s0 + sl0;
    short8 a, b2;
#pragma unroll
    for (int j = 0; j < 8; j++) {
      a[j]  = (short)tile[sl0 + j][dl];
      b2[j] = (short)tile[sl0 + 8 + j][dl];
    }
    *(short8*)dst = a;
    *(short8*)(dst + 8) = b2;
  }
}

// ---------------- RMSNorm: fp32 in -> bf16 out, one row per block ----------------
__global__ __launch_bounds__(256)
void rmsnorm_f32_bf16(const float* __restrict__ x, const float* __restrict__ w,
                      unsigned short* __restrict__ out) {
  __shared__ float red[4];
  const int row = blockIdx.x, t = threadIdx.x;
  const float4 v = ((const float4*)(x + (size_t)row * 1024))[t];
  float ss = v.x * v.x + v.y * v.y + v.z * v.z + v.w * v.w;
#pragma unroll
  for (int d = 1; d < 64; d <<= 1) ss += __shfl_xor(ss, d);
  if ((t & 63) == 0) red[t >> 6] = ss;
  __syncthreads();
  const float tot = red[0] + red[1] + red[2] + red[3];
  const float r = rsqrtf(tot * (1.0f / 1024.0f) + 1e-6f);
  const float4 wv = ((const float4*)w)[t];
  ushort4 o;
  o.x = f2bf(v.x * r * wv.x);
  o.y = f2bf(v.y * r * wv.y);
  o.z = f2bf(v.z * r * wv.z);
  o.w = f2bf(v.w * r * wv.w);
  *((ushort4*)(out + (size_t)row * 1024 + t * 4)) = o;
}

// ---------------- flash attention: 8 waves x 32 q-rows, kb2-split + s_setprio (T5) --------
// R12/R16/R18 winner, unchanged.
__global__ __launch_bounds__(512, 4)
void attn(const unsigned short* __restrict__ qkv, const unsigned short* __restrict__ Vt,
          unsigned short* __restrict__ ctx) {
  __shared__ alignas(16) unsigned short Ks[2][64 * 64];
  __shared__ alignas(16) unsigned short Vs[2][64 * 64];
  __shared__ alignas(16) unsigned short Plds[8][32 * 72];
  const int tid = threadIdx.x, lane = tid & 63, wid = tid >> 6;
  const int qb = blockIdx.x & 7, bh = blockIdx.x >> 3;
  const int b = bh >> 4, h = bh & 15;
  const int g = lane >> 4, c = lane & 15;
  const int qrow0 = qb * 256 + wid * 32;

  const unsigned short* Kb = qkv + (size_t)b * SEQ * 3072 + 1024 + h * 64;
  const unsigned short* Vb = Vt + (size_t)bh * 64 * SEQ;

  const int srow = lane >> 3;
  const int swz = (((lane & 7) ^ srow) << 3);

  short8 bq[2][2];
#pragma unroll
  for (int m = 0; m < 2; m++)
#pragma unroll
    for (int kb = 0; kb < 2; kb++) {
      const int sq = qrow0 + m * 16 + c;
      bq[m][kb] = *(const short8*)(qkv + (size_t)(b * SEQ + sq) * 3072 + h * 64 + kb * 32 + g * 8);
    }

  short8 ones;
#pragma unroll
  for (int j = 0; j < 8; j++) ones[j] = (short)0x3F80;

  f32x4 o[2][4];
  f32x4 lacc[2];
#pragma unroll
  for (int m = 0; m < 2; m++) {
#pragma unroll
    for (int nc = 0; nc < 4; nc++) o[m][nc] = f32x4{0.f, 0.f, 0.f, 0.f};
    lacc[m] = f32x4{0.f, 0.f, 0.f, 0.f};
  }

  unsigned short* pw = &Plds[wid][0];

  async_ld16(Kb + (size_t)(wid * 8 + srow) * 3072 + swz, &Ks[0][wid * 512]);
  async_ld16(Vb + (size_t)(wid * 8 + srow) * 2048 + swz, &Vs[0][wid * 512]);
  __syncthreads();

  for (int tt = 0; tt < SEQ / 128; ++tt) {
#pragma unroll
    for (int half = 0; half < 2; ++half) {
      const int t = tt * 2 + half;                  // buf == half (compile-time)
      const char* ksb = (const char*)Ks + half * 8192;
      const char* vsb = (const char*)Vs + half * 8192;
      if (t + 1 < SEQ / 64) {
        const int kt2 = (t + 1) * 64;
        async_ld16(Kb + (size_t)(kt2 + wid * 8 + srow) * 3072 + swz, &Ks[half ^ 1][wid * 512]);
        async_ld16(Vb + (size_t)(wid * 8 + srow) * 2048 + kt2 + swz, &Vs[half ^ 1][wid * 512]);
      }

      // QK: sacc[m][n] reg r = (pre-scaled) S^T[k = n*16+g*4+r][q = m*16+c]
      f32x4 sacc[2][4];
#pragma unroll
      for (int m = 0; m < 2; m++)
#pragma unroll
        for (int n = 0; n < 4; n++) sacc[m][n] = f32x4{0.f, 0.f, 0.f, 0.f};
#pragma unroll
      for (int kb = 0; kb < 2; ++kb) {
        short8 ak[4];
#pragma unroll
        for (int n = 0; n < 4; n++)
          ak[n] = *(const short8*)(ksb + (n * 16 + c) * 128 +
                                   ((kb * 64 + g * 16) ^ ((c & 7) << 4)));
        __builtin_amdgcn_s_setprio(1);
#pragma unroll
        for (int m = 0; m < 2; m++)
#pragma unroll
          for (int n = 0; n < 4; n++)
            sacc[m][n] = __builtin_amdgcn_mfma_f32_16x16x32_bf16(ak[n], bq[m][kb], sacc[m][n], 0, 0, 0);
        __builtin_amdgcn_s_setprio(0);
      }

      // per 32-k half: exp+pack (n = 2*kb2, 2*kb2+1) -> pa -> PV half; PV MFMA of half 0
      // overlaps the exp chain of half 1.
#pragma unroll
      for (int kb2 = 0; kb2 < 2; ++kb2) {
#pragma unroll
        for (int m = 0; m < 2; m++) {
          char* rowp = (char*)pw + (m * 16 + c) * 144;
#pragma unroll
          for (int nn = 0; nn < 2; nn++) {
            const int n = kb2 * 2 + nn;
            const float p0 = __builtin_amdgcn_exp2f(sacc[m][n][0]);
            const float p1 = __builtin_amdgcn_exp2f(sacc[m][n][1]);
            const float p2 = __builtin_amdgcn_exp2f(sacc[m][n][2]);
            const float p3 = __builtin_amdgcn_exp2f(sacc[m][n][3]);
            *(unsigned*)(rowp + (n * 16 + g * 4) * 2)     = pack_bf16x2(p0, p1);
            *(unsigned*)(rowp + (n * 16 + g * 4) * 2 + 4) = pack_bf16x2(p2, p3);
          }
        }
        short8 pa[2];
#pragma unroll
        for (int m = 0; m < 2; m++)
          pa[m] = *(const short8*)((const char*)pw + (m * 16 + c) * 144 + kb2 * 64 + g * 16);
        __builtin_amdgcn_s_setprio(1);
#pragma unroll
        for (int nc = 0; nc < 4; nc++) {
          const short8 vb = *(const short8*)(vsb + (nc * 16 + c) * 128 +
                                             ((kb2 * 64 + g * 16) ^ ((c & 7) << 4)));
#pragma unroll
          for (int m = 0; m < 2; m++)
            o[m][nc] = __builtin_amdgcn_mfma_f32_16x16x32_bf16(pa[m], vb, o[m][nc], 0, 0, 0);
        }
#pragma unroll
        for (int m = 0; m < 2; m++)
          lacc[m] = __builtin_amdgcn_mfma_f32_16x16x32_bf16(pa[m], ones, lacc[m], 0, 0, 0);
        __builtin_amdgcn_s_setprio(0);
      }
      __syncthreads();
    }
  }

  // epilogue: lacc[m][r] = l[q = m*16+g*4+r] — same row mapping as o[m][nc][r]; no shuffles
#pragma unroll
  for (int m = 0; m < 2; m++)
#pragma unroll
    for (int r = 0; r < 4; r++) {
      const float linv = 1.0f / lacc[m][r];
      const int sq = qrow0 + m * 16 + g * 4 + r;
#pragma unroll
      for (int nc = 0; nc < 4; nc++) {
        const int d = h * 64 + nc * 16 + c;
        ctx[(size_t)(b * SEQ + sq) * 1024 + d] = f2bf(o[m][nc][r] * linv);
      }
    }
}

extern "C" void kernel_launch(void* const* d_in, const int* in_sizes, int n_in,
                              void* d_out, int out_size, void* d_ws, size_t ws_size,
                              hipStream_t stream) {
  const float* x     = (const float*)d_in[0];
  const float* W_qkv = (const float*)d_in[1];
  const float* b_qkv = (const float*)d_in[2];
  const float* W_o   = (const float*)d_in[3];
  const float* b_o   = (const float*)d_in[4];
  const float* W_ff1 = (const float*)d_in[5];
  const float* b_ff1 = (const float*)d_in[6];
  const float* W_ff2 = (const float*)d_in[7];
  const float* b_ff2 = (const float*)d_in[8];
  const float* n1    = (const float*)d_in[9];
  const float* n2    = (const float*)d_in[10];
  float* out = (float*)d_out;

  char* p = (char*)d_ws;
  unsigned short* Wt_qkv = (unsigned short*)p; p += (size_t)3072 * 1024 * 2;
  unsigned short* Wt_o   = (unsigned short*)p; p += (size_t)1024 * 1024 * 2;
  unsigned short* Wt_ff1 = (unsigned short*)p; p += (size_t)4096 * 1024 * 2;
  unsigned short* Wt_ff2 = (unsigned short*)p; p += (size_t)1024 * 4096 * 2;
  unsigned short* xn  = (unsigned short*)p; p += (size_t)8192 * 1024 * 2;  // reused as ctx
  unsigned short* qkv = (unsigned short*)p; p += (size_t)8192 * 3072 * 2;  // reused as attn_out(fp32)
  unsigned short* Vt  = (unsigned short*)p; p += (size_t)8192 * 1024 * 2;  // reused as yn
  unsigned short* h   = (unsigned short*)p; p += (size_t)8192 * 4096 * 2;

  unsigned short* ctxb = xn;
  float* attn_out = (float*)qkv;
  unsigned short* yn = Vt;

  wtrans<<<dim3(48, 16), 256, 0, stream>>>(W_qkv, Wt_qkv, 1024, 3072);
  wtrans<<<dim3(16, 16), 256, 0, stream>>>(W_o,   Wt_o,   1024, 1024);
  wtrans<<<dim3(64, 16), 256, 0, stream>>>(W_ff1, Wt_ff1, 1024, 4096);
  wtrans<<<dim3(16, 64), 256, 0, stream>>>(W_ff2, Wt_ff2, 4096, 1024);

  rmsnorm_f32_bf16<<<8192, 256, 0, stream>>>(x, n1, xn);
  gemm_bf16<3><<<24 * 64, 256, 0, stream>>>(xn, Wt_qkv, b_qkv, (void*)qkv, 8192, 3072, 1024);
  vtrans<<<2048, 256, 0, stream>>>(qkv, Vt);
  attn<<<512, 512, 0, stream>>>(qkv, Vt, ctxb);
  gemm_bf16<2><<<8 * 64, 256, 0, stream>>>(ctxb, Wt_o, b_o, (void*)attn_out, 8192, 1024, 1024);
  rmsnorm_f32_bf16<<<8192, 256, 0, stream>>>(attn_out, n2, yn);
  gemm_bf16<1><<<32 * 64, 256, 0, stream>>>(yn, Wt_ff1, b_ff1, (void*)h, 8192, 4096, 1024);
  gemm_bf16<2><<<8 * 64, 256, 0, stream>>>(h, Wt_ff2, b_ff2, (void*)out, 8192, 1024, 4096);
}

// Round 21
// 378.801 us; speedup vs baseline: 1.1081x; 1.0065x over previous
//
#include <hip/hip_runtime.h>
#include <hip/hip_bf16.h>

#define SEQ 2048

typedef __attribute__((ext_vector_type(8))) short short8;
typedef __attribute__((ext_vector_type(4))) float f32x4;

__device__ __forceinline__ unsigned short f2bf(float f) {
  unsigned u = __float_as_uint(f);
  u += 0x7fffu + ((u >> 16) & 1u);
  return (unsigned short)(u >> 16);
}

__device__ __forceinline__ float bf2f(unsigned short v) {
  return __uint_as_float(((unsigned)v) << 16);
}

// Pack two f32 -> bf16x2 via the COMPILER-VISIBLE HIP conversion (no inline asm).
// R13-R16 lesson: v_exp_f32 is a TRANS op with a result-use wait-state; the hazard
// recognizer does NOT pad when the consumer is an opaque inline-asm block.
__device__ __forceinline__ unsigned pack_bf16x2(float lo, float hi) {
  __hip_bfloat162 h = __float22bfloat162_rn(float2{lo, hi});
  unsigned r;
  __builtin_memcpy(&r, &h, 4);
  return r;
}

// tanh-form GELU: x * sigmoid(1.5957691*x*(1+0.044715*x^2)). Max |err| vs erf-GELU ~3e-4.
__device__ __forceinline__ float gelu_fast(float x) {
  const float u = 1.5957691f * x * __builtin_fmaf(0.044715f, x * x, 1.0f);
  const float e = __builtin_amdgcn_exp2f(-1.4426950408889634f * u);  // exp(-u)
  return x * __builtin_amdgcn_rcpf(1.0f + e);
}

__device__ __forceinline__ void async_ld16(const unsigned short* g, unsigned short* l) {
  __builtin_amdgcn_global_load_lds((const __attribute__((address_space(1))) unsigned int*)g,
                                   (__attribute__((address_space(3))) unsigned int*)l, 16, 0, 0);
}

// ---------------- 128x128 GEMM (verified m97-class) + T1 supertile XCD swizzle ------------
// EPI 0: bf16 store; EPI 1: gelu+bf16; EPI 2: fp32; EPI 3: bf16 with Q-scale fold.
// R20: 8x4 supertile decode inside XCD-chunked remap — per-XCD window 3MB < 4MB L2;
// each XCD runs one row-group end-to-end so A is fetched exactly once globally
// (FETCH 82->66MB, total -17µs). R19's by-fastest decode thrashed A (266MB) — keep 8x4.
template<int EPI>
__global__ __launch_bounds__(256)
void gemm_bf16(const unsigned short* __restrict__ A,
               const unsigned short* __restrict__ Bt,
               const float* __restrict__ bias,
               void* __restrict__ Cout,
               int M, int N, int K) {
  __shared__ alignas(16) unsigned short As[128 * 64];
  __shared__ alignas(16) unsigned short Bs[128 * 64];
  const int tid = threadIdx.x;
  const int lane = tid & 63;
  const int wid = tid >> 6;
  const int wr = wid >> 1, wc = wid & 1;

  // T1: XCD-chunked bijective remap, supertile decode.
  const int nwg = gridDim.x;
  const int lin = (blockIdx.x & 7) * (nwg >> 3) + (blockIdx.x >> 3);
  const int nstx = N >> 9;              // (N/128)/4 supertile columns
  const int st = lin >> 5;              // 32 blocks per 8x4 supertile
  const int i = lin & 31;
  const int byg = st / nstx;            // row-group-major: A-rows shared per XCD
  const int bxg = st - byg * nstx;
  const int rowbase = (byg * 8 + (i >> 2)) * 128;
  const int colbase = (bxg * 4 + (i & 3)) * 128;
  const int g = lane >> 4, c = lane & 15;

  f32x4 acc[4][4];
#pragma unroll
  for (int m = 0; m < 4; m++)
#pragma unroll
    for (int n = 0; n < 4; n++) acc[m][n] = f32x4{0.f, 0.f, 0.f, 0.f};

  const int lrow = lane >> 3;
  const int swzel = (((lane & 7) ^ lrow) << 3);
  const unsigned short* gA = A + (size_t)(rowbase + wid * 32 + lrow) * K + swzel;
  const unsigned short* gB = Bt + (size_t)(colbase + wid * 32 + lrow) * K + swzel;
  unsigned short* lA = As + wid * 2048;
  unsigned short* lB = Bs + wid * 2048;

  for (int kt = 0; kt < K; kt += 64) {
#pragma unroll
    for (int i2 = 0; i2 < 4; i2++) async_ld16(gA + kt + (size_t)i2 * 8 * K, lA + i2 * 512);
#pragma unroll
    for (int i2 = 0; i2 < 4; i2++) async_ld16(gB + kt + (size_t)i2 * 8 * K, lB + i2 * 512);
    __syncthreads();
#pragma unroll
    for (int kb = 0; kb < 2; ++kb) {
      short8 av[4], bv[4];
#pragma unroll
      for (int m = 0; m < 4; m++) {
        const int row = wr * 64 + m * 16 + c;
        const int cb = (kb * 64 + g * 16) ^ ((row & 7) << 4);
        av[m] = *(const short8*)((const char*)As + row * 128 + cb);
      }
#pragma unroll
      for (int n = 0; n < 4; n++) {
        const int row = wc * 64 + n * 16 + c;
        const int cb = (kb * 64 + g * 16) ^ ((row & 7) << 4);
        bv[n] = *(const short8*)((const char*)Bs + row * 128 + cb);
      }
#pragma unroll
      for (int m = 0; m < 4; m++)
#pragma unroll
        for (int n = 0; n < 4; n++)
          acc[m][n] = __builtin_amdgcn_mfma_f32_16x16x32_bf16(av[m], bv[n], acc[m][n], 0, 0, 0);
    }
    __syncthreads();
  }

#pragma unroll
  for (int m = 0; m < 4; m++) {
    const int row0 = rowbase + wr * 64 + m * 16 + g * 4;
#pragma unroll
    for (int n = 0; n < 4; n++) {
      const int col = colbase + wc * 64 + n * 16 + c;
      const float bb = bias[col];
#pragma unroll
      for (int r = 0; r < 4; r++) {
        float v = acc[m][n][r] + bb;
        const size_t idx = (size_t)(row0 + r) * N + col;
        if (EPI == 1) {
          v = gelu_fast(v);
          ((unsigned short*)Cout)[idx] = f2bf(v);
        } else if (EPI == 2) {
          ((float*)Cout)[idx] = v;
        } else if (EPI == 3) {
          v = (col < 1024) ? v * 0.18033688f : v;  // fold (1/sqrt(64))*log2(e) into Q
          ((unsigned short*)Cout)[idx] = f2bf(v);
        } else {
          ((unsigned short*)Cout)[idx] = f2bf(v);
        }
      }
    }
  }
}

// ---------------- weight transpose-convert: W fp32 [K][N] -> Wt bf16 [N][K] ----------------
__global__ __launch_bounds__(256)
void wtrans(const float* __restrict__ W, unsigned short* __restrict__ Wt, int K, int N) {
  __shared__ unsigned short tile[64][72];
  const int n0 = blockIdx.x * 64, k0 = blockIdx.y * 64;
  const int t = threadIdx.x;
  {
    const int kl = t >> 2, nl0 = (t & 3) * 16;
    const float4* src = (const float4*)(W + (size_t)(k0 + kl) * N + n0 + nl0);
#pragma unroll
    for (int i = 0; i < 4; i++) {
      float4 v = src[i];
      tile[kl][nl0 + i * 4 + 0] = f2bf(v.x);
      tile[kl][nl0 + i * 4 + 1] = f2bf(v.y);
      tile[kl][nl0 + i * 4 + 2] = f2bf(v.z);
      tile[kl][nl0 + i * 4 + 3] = f2bf(v.w);
    }
  }
  __syncthreads();
  {
    const int nl = t >> 2, kl0 = (t & 3) * 16;
    unsigned short* dst = Wt + (size_t)(n0 + nl) * K + k0 + kl0;
    short8 a, b2;
#pragma unroll
    for (int j = 0; j < 8; j++) {
      a[j]  = (short)tile[kl0 + j][nl];
      b2[j] = (short)tile[kl0 + 8 + j][nl];
    }
    *(short8*)dst = a;
    *(short8*)(dst + 8) = b2;
  }
}

// ---------------- V transpose: qkv V-part [b][s][h][dh] -> Vt [b*h][dh][s] ----------------
__global__ __launch_bounds__(256)
void vtrans(const unsigned short* __restrict__ qkv, unsigned short* __restrict__ Vt) {
  __shared__ unsigned short tile[64][72];
  const int blk = blockIdx.x;
  const int st = blk & 31, bh = blk >> 5;
  const int b = bh >> 4, h = bh & 15;
  const int s0 = st * 64;
  const int t = threadIdx.x;
  {
    const int sl = t >> 2, d0 = (t & 3) * 16;
    const unsigned short* src = qkv + (size_t)(b * SEQ + s0 + sl) * 3072 + 2048 + h * 64 + d0;
    short8 v0 = *(const short8*)src;
    short8 v1 = *(const short8*)(src + 8);
#pragma unroll
    for (int j = 0; j < 8; j++) {
      tile[sl][d0 + j] = (unsigned short)v0[j];
      tile[sl][d0 + 8 + j] = (unsigned short)v1[j];
    }
  }
  __syncthreads();
  {
    const int dl = t >> 2, sl0 = (t & 3) * 16;
    unsigned short* dst = Vt + ((size_t)bh * 64 + dl) * SEQ + s0 + sl0;
    short8 a, b2;
#pragma unroll
    for (int j = 0; j < 8; j++) {
      a[j]  = (short)tile[sl0 + j][dl];
      b2[j] = (short)tile[sl0 + 8 + j][dl];
    }
    *(short8*)dst = a;
    *(short8*)(dst + 8) = b2;
  }
}

// ---------------- RMSNorm: fp32 in -> bf16 out, one row per block ----------------
__global__ __launch_bounds__(256)
void rmsnorm_f32_bf16(const float* __restrict__ x, const float* __restrict__ w,
                      unsigned short* __restrict__ out) {
  __shared__ float red[4];
  const int row = blockIdx.x, t = threadIdx.x;
  const float4 v = ((const float4*)(x + (size_t)row * 1024))[t];
  float ss = v.x * v.x + v.y * v.y + v.z * v.z + v.w * v.w;
#pragma unroll
  for (int d = 1; d < 64; d <<= 1) ss += __shfl_xor(ss, d);
  if ((t & 63) == 0) red[t >> 6] = ss;
  __syncthreads();
  const float tot = red[0] + red[1] + red[2] + red[3];
  const float r = rsqrtf(tot * (1.0f / 1024.0f) + 1e-6f);
  const float4 wv = ((const float4*)w)[t];
  ushort4 o;
  o.x = f2bf(v.x * r * wv.x);
  o.y = f2bf(v.y * r * wv.y);
  o.z = f2bf(v.z * r * wv.z);
  o.w = f2bf(v.w * r * wv.w);
  *((ushort4*)(out + (size_t)row * 1024 + t * 4)) = o;
}

// ---------------- RMSNorm: bf16 in -> bf16 out (R21: Wo stores bf16, halves traffic) ------
__global__ __launch_bounds__(256)
void rmsnorm_bf16_bf16(const unsigned short* __restrict__ x, const float* __restrict__ w,
                       unsigned short* __restrict__ out) {
  __shared__ float red[4];
  const int row = blockIdx.x, t = threadIdx.x;
  const ushort4 v = ((const ushort4*)(x + (size_t)row * 1024))[t];
  const float f0 = bf2f(v.x), f1 = bf2f(v.y), f2 = bf2f(v.z), f3 = bf2f(v.w);
  float ss = f0 * f0 + f1 * f1 + f2 * f2 + f3 * f3;
#pragma unroll
  for (int d = 1; d < 64; d <<= 1) ss += __shfl_xor(ss, d);
  if ((t & 63) == 0) red[t >> 6] = ss;
  __syncthreads();
  const float tot = red[0] + red[1] + red[2] + red[3];
  const float r = rsqrtf(tot * (1.0f / 1024.0f) + 1e-6f);
  const float4 wv = ((const float4*)w)[t];
  ushort4 o;
  o.x = f2bf(f0 * r * wv.x);
  o.y = f2bf(f1 * r * wv.y);
  o.z = f2bf(f2 * r * wv.z);
  o.w = f2bf(f3 * r * wv.w);
  *((ushort4*)(out + (size_t)row * 1024 + t * 4)) = o;
}

// ---------------- flash attention: 8 waves x 32 q-rows, kb2-split + s_setprio (T5) --------
// R12/R16/R18 winner, unchanged.
__global__ __launch_bounds__(512, 4)
void attn(const unsigned short* __restrict__ qkv, const unsigned short* __restrict__ Vt,
          unsigned short* __restrict__ ctx) {
  __shared__ alignas(16) unsigned short Ks[2][64 * 64];
  __shared__ alignas(16) unsigned short Vs[2][64 * 64];
  __shared__ alignas(16) unsigned short Plds[8][32 * 72];
  const int tid = threadIdx.x, lane = tid & 63, wid = tid >> 6;
  const int qb = blockIdx.x & 7, bh = blockIdx.x >> 3;
  const int b = bh >> 4, h = bh & 15;
  const int g = lane >> 4, c = lane & 15;
  const int qrow0 = qb * 256 + wid * 32;

  const unsigned short* Kb = qkv + (size_t)b * SEQ * 3072 + 1024 + h * 64;
  const unsigned short* Vb = Vt + (size_t)bh * 64 * SEQ;

  const int srow = lane >> 3;
  const int swz = (((lane & 7) ^ srow) << 3);

  short8 bq[2][2];
#pragma unroll
  for (int m = 0; m < 2; m++)
#pragma unroll
    for (int kb = 0; kb < 2; kb++) {
      const int sq = qrow0 + m * 16 + c;
      bq[m][kb] = *(const short8*)(qkv + (size_t)(b * SEQ + sq) * 3072 + h * 64 + kb * 32 + g * 8);
    }

  short8 ones;
#pragma unroll
  for (int j = 0; j < 8; j++) ones[j] = (short)0x3F80;

  f32x4 o[2][4];
  f32x4 lacc[2];
#pragma unroll
  for (int m = 0; m < 2; m++) {
#pragma unroll
    for (int nc = 0; nc < 4; nc++) o[m][nc] = f32x4{0.f, 0.f, 0.f, 0.f};
    lacc[m] = f32x4{0.f, 0.f, 0.f, 0.f};
  }

  unsigned short* pw = &Plds[wid][0];

  async_ld16(Kb + (size_t)(wid * 8 + srow) * 3072 + swz, &Ks[0][wid * 512]);
  async_ld16(Vb + (size_t)(wid * 8 + srow) * 2048 + swz, &Vs[0][wid * 512]);
  __syncthreads();

  for (int tt = 0; tt < SEQ / 128; ++tt) {
#pragma unroll
    for (int half = 0; half < 2; ++half) {
      const int t = tt * 2 + half;                  // buf == half (compile-time)
      const char* ksb = (const char*)Ks + half * 8192;
      const char* vsb = (const char*)Vs + half * 8192;
      if (t + 1 < SEQ / 64) {
        const int kt2 = (t + 1) * 64;
        async_ld16(Kb + (size_t)(kt2 + wid * 8 + srow) * 3072 + swz, &Ks[half ^ 1][wid * 512]);
        async_ld16(Vb + (size_t)(wid * 8 + srow) * 2048 + kt2 + swz, &Vs[half ^ 1][wid * 512]);
      }

      // QK: sacc[m][n] reg r = (pre-scaled) S^T[k = n*16+g*4+r][q = m*16+c]
      f32x4 sacc[2][4];
#pragma unroll
      for (int m = 0; m < 2; m++)
#pragma unroll
        for (int n = 0; n < 4; n++) sacc[m][n] = f32x4{0.f, 0.f, 0.f, 0.f};
#pragma unroll
      for (int kb = 0; kb < 2; ++kb) {
        short8 ak[4];
#pragma unroll
        for (int n = 0; n < 4; n++)
          ak[n] = *(const short8*)(ksb + (n * 16 + c) * 128 +
                                   ((kb * 64 + g * 16) ^ ((c & 7) << 4)));
        __builtin_amdgcn_s_setprio(1);
#pragma unroll
        for (int m = 0; m < 2; m++)
#pragma unroll
          for (int n = 0; n < 4; n++)
            sacc[m][n] = __builtin_amdgcn_mfma_f32_16x16x32_bf16(ak[n], bq[m][kb], sacc[m][n], 0, 0, 0);
        __builtin_amdgcn_s_setprio(0);
      }

      // per 32-k half: exp+pack (n = 2*kb2, 2*kb2+1) -> pa -> PV half; PV MFMA of half 0
      // overlaps the exp chain of half 1.
#pragma unroll
      for (int kb2 = 0; kb2 < 2; ++kb2) {
#pragma unroll
        for (int m = 0; m < 2; m++) {
          char* rowp = (char*)pw + (m * 16 + c) * 144;
#pragma unroll
          for (int nn = 0; nn < 2; nn++) {
            const int n = kb2 * 2 + nn;
            const float p0 = __builtin_amdgcn_exp2f(sacc[m][n][0]);
            const float p1 = __builtin_amdgcn_exp2f(sacc[m][n][1]);
            const float p2 = __builtin_amdgcn_exp2f(sacc[m][n][2]);
            const float p3 = __builtin_amdgcn_exp2f(sacc[m][n][3]);
            *(unsigned*)(rowp + (n * 16 + g * 4) * 2)     = pack_bf16x2(p0, p1);
            *(unsigned*)(rowp + (n * 16 + g * 4) * 2 + 4) = pack_bf16x2(p2, p3);
          }
        }
        short8 pa[2];
#pragma unroll
        for (int m = 0; m < 2; m++)
          pa[m] = *(const short8*)((const char*)pw + (m * 16 + c) * 144 + kb2 * 64 + g * 16);
        __builtin_amdgcn_s_setprio(1);
#pragma unroll
        for (int nc = 0; nc < 4; nc++) {
          const short8 vb = *(const short8*)(vsb + (nc * 16 + c) * 128 +
                                             ((kb2 * 64 + g * 16) ^ ((c & 7) << 4)));
#pragma unroll
          for (int m = 0; m < 2; m++)
            o[m][nc] = __builtin_amdgcn_mfma_f32_16x16x32_bf16(pa[m], vb, o[m][nc], 0, 0, 0);
        }
#pragma unroll
        for (int m = 0; m < 2; m++)
          lacc[m] = __builtin_amdgcn_mfma_f32_16x16x32_bf16(pa[m], ones, lacc[m], 0, 0, 0);
        __builtin_amdgcn_s_setprio(0);
      }
      __syncthreads();
    }
  }

  // epilogue: lacc[m][r] = l[q = m*16+g*4+r] — same row mapping as o[m][nc][r]; no shuffles
#pragma unroll
  for (int m = 0; m < 2; m++)
#pragma unroll
    for (int r = 0; r < 4; r++) {
      const float linv = 1.0f / lacc[m][r];
      const int sq = qrow0 + m * 16 + g * 4 + r;
#pragma unroll
      for (int nc = 0; nc < 4; nc++) {
        const int d = h * 64 + nc * 16 + c;
        ctx[(size_t)(b * SEQ + sq) * 1024 + d] = f2bf(o[m][nc][r] * linv);
      }
    }
}

extern "C" void kernel_launch(void* const* d_in, const int* in_sizes, int n_in,
                              void* d_out, int out_size, void* d_ws, size_t ws_size,
                              hipStream_t stream) {
  const float* x     = (const float*)d_in[0];
  const float* W_qkv = (const float*)d_in[1];
  const float* b_qkv = (const float*)d_in[2];
  const float* W_o   = (const float*)d_in[3];
  const float* b_o   = (const float*)d_in[4];
  const float* W_ff1 = (const float*)d_in[5];
  const float* b_ff1 = (const float*)d_in[6];
  const float* W_ff2 = (const float*)d_in[7];
  const float* b_ff2 = (const float*)d_in[8];
  const float* n1    = (const float*)d_in[9];
  const float* n2    = (const float*)d_in[10];
  float* out = (float*)d_out;

  char* p = (char*)d_ws;
  unsigned short* Wt_qkv = (unsigned short*)p; p += (size_t)3072 * 1024 * 2;
  unsigned short* Wt_o   = (unsigned short*)p; p += (size_t)1024 * 1024 * 2;
  unsigned short* Wt_ff1 = (unsigned short*)p; p += (size_t)4096 * 1024 * 2;
  unsigned short* Wt_ff2 = (unsigned short*)p; p += (size_t)1024 * 4096 * 2;
  unsigned short* xn  = (unsigned short*)p; p += (size_t)8192 * 1024 * 2;  // reused as ctx
  unsigned short* qkv = (unsigned short*)p; p += (size_t)8192 * 3072 * 2;  // reused as attn_out(bf16)
  unsigned short* Vt  = (unsigned short*)p; p += (size_t)8192 * 1024 * 2;  // reused as yn
  unsigned short* h   = (unsigned short*)p; p += (size_t)8192 * 4096 * 2;

  unsigned short* ctxb = xn;
  unsigned short* attn_out = qkv;   // bf16 now (R21): Wo stores bf16, rmsnorm reads bf16
  unsigned short* yn = Vt;

  wtrans<<<dim3(48, 16), 256, 0, stream>>>(W_qkv, Wt_qkv, 1024, 3072);
  wtrans<<<dim3(16, 16), 256, 0, stream>>>(W_o,   Wt_o,   1024, 1024);
  wtrans<<<dim3(64, 16), 256, 0, stream>>>(W_ff1, Wt_ff1, 1024, 4096);
  wtrans<<<dim3(16, 64), 256, 0, stream>>>(W_ff2, Wt_ff2, 4096, 1024);

  rmsnorm_f32_bf16<<<8192, 256, 0, stream>>>(x, n1, xn);
  gemm_bf16<3><<<24 * 64, 256, 0, stream>>>(xn, Wt_qkv, b_qkv, (void*)qkv, 8192, 3072, 1024);
  vtrans<<<2048, 256, 0, stream>>>(qkv, Vt);
  attn<<<512, 512, 0, stream>>>(qkv, Vt, ctxb);
  gemm_bf16<0><<<8 * 64, 256, 0, stream>>>(ctxb, Wt_o, b_o, (void*)attn_out, 8192, 1024, 1024);
  rmsnorm_bf16_bf16<<<8192, 256, 0, stream>>>(attn_out, n2, yn);
  gemm_bf16<1><<<32 * 64, 256, 0, stream>>>(yn, Wt_ff1, b_ff1, (void*)h, 8192, 4096, 1024);
  gemm_bf16<2><<<8 * 64, 256, 0, stream>>>(h, Wt_ff2, b_ff2, (void*)out, 8192, 1024, 4096);
}

// Round 22
// 372.631 us; speedup vs baseline: 1.1264x; 1.0166x over previous
//
#include <hip/hip_runtime.h>
#include <hip/hip_bf16.h>

#define SEQ 2048

typedef __attribute__((ext_vector_type(8))) short short8;
typedef __attribute__((ext_vector_type(4))) float f32x4;

__device__ __forceinline__ unsigned short f2bf(float f) {
  unsigned u = __float_as_uint(f);
  u += 0x7fffu + ((u >> 16) & 1u);
  return (unsigned short)(u >> 16);
}

__device__ __forceinline__ float bf2f(unsigned short v) {
  return __uint_as_float(((unsigned)v) << 16);
}

// Pack two f32 -> bf16x2 via the COMPILER-VISIBLE HIP conversion (no inline asm).
// R13-R16 lesson: v_exp_f32 is a TRANS op with a result-use wait-state; the hazard
// recognizer does NOT pad when the consumer is an opaque inline-asm block.
__device__ __forceinline__ unsigned pack_bf16x2(float lo, float hi) {
  __hip_bfloat162 h = __float22bfloat162_rn(float2{lo, hi});
  unsigned r;
  __builtin_memcpy(&r, &h, 4);
  return r;
}

// tanh-form GELU: x * sigmoid(1.5957691*x*(1+0.044715*x^2)). Max |err| vs erf-GELU ~3e-4.
__device__ __forceinline__ float gelu_fast(float x) {
  const float u = 1.5957691f * x * __builtin_fmaf(0.044715f, x * x, 1.0f);
  const float e = __builtin_amdgcn_exp2f(-1.4426950408889634f * u);  // exp(-u)
  return x * __builtin_amdgcn_rcpf(1.0f + e);
}

__device__ __forceinline__ void async_ld16(const unsigned short* g, unsigned short* l) {
  __builtin_amdgcn_global_load_lds((const __attribute__((address_space(1))) unsigned int*)g,
                                   (__attribute__((address_space(3))) unsigned int*)l, 16, 0, 0);
}

// ---------------- 128x128 GEMM (verified m97-class) + T1 supertile XCD swizzle ------------
// EPI 0: bf16 store; EPI 1: gelu+bf16; EPI 2: fp32; EPI 3: bf16 with Q-scale fold.
// R20: 8x4 supertile decode inside XCD-chunked remap — per-XCD window 3MB < 4MB L2;
// each XCD runs one row-group end-to-end so A is fetched exactly once globally
// (FETCH 82->66MB, total -17µs). R19's by-fastest decode thrashed A (266MB) — keep 8x4.
template<int EPI>
__global__ __launch_bounds__(256)
void gemm_bf16(const unsigned short* __restrict__ A,
               const unsigned short* __restrict__ Bt,
               const float* __restrict__ bias,
               void* __restrict__ Cout,
               int M, int N, int K) {
  __shared__ alignas(16) unsigned short As[128 * 64];
  __shared__ alignas(16) unsigned short Bs[128 * 64];
  const int tid = threadIdx.x;
  const int lane = tid & 63;
  const int wid = tid >> 6;
  const int wr = wid >> 1, wc = wid & 1;

  // T1: XCD-chunked bijective remap, supertile decode.
  const int nwg = gridDim.x;
  const int lin = (blockIdx.x & 7) * (nwg >> 3) + (blockIdx.x >> 3);
  const int nstx = N >> 9;              // (N/128)/4 supertile columns
  const int st = lin >> 5;              // 32 blocks per 8x4 supertile
  const int i = lin & 31;
  const int byg = st / nstx;            // row-group-major: A-rows shared per XCD
  const int bxg = st - byg * nstx;
  const int rowbase = (byg * 8 + (i >> 2)) * 128;
  const int colbase = (bxg * 4 + (i & 3)) * 128;
  const int g = lane >> 4, c = lane & 15;

  f32x4 acc[4][4];
#pragma unroll
  for (int m = 0; m < 4; m++)
#pragma unroll
    for (int n = 0; n < 4; n++) acc[m][n] = f32x4{0.f, 0.f, 0.f, 0.f};

  const int lrow = lane >> 3;
  const int swzel = (((lane & 7) ^ lrow) << 3);
  const unsigned short* gA = A + (size_t)(rowbase + wid * 32 + lrow) * K + swzel;
  const unsigned short* gB = Bt + (size_t)(colbase + wid * 32 + lrow) * K + swzel;
  unsigned short* lA = As + wid * 2048;
  unsigned short* lB = Bs + wid * 2048;

  for (int kt = 0; kt < K; kt += 64) {
#pragma unroll
    for (int i2 = 0; i2 < 4; i2++) async_ld16(gA + kt + (size_t)i2 * 8 * K, lA + i2 * 512);
#pragma unroll
    for (int i2 = 0; i2 < 4; i2++) async_ld16(gB + kt + (size_t)i2 * 8 * K, lB + i2 * 512);
    __syncthreads();
#pragma unroll
    for (int kb = 0; kb < 2; ++kb) {
      short8 av[4], bv[4];
#pragma unroll
      for (int m = 0; m < 4; m++) {
        const int row = wr * 64 + m * 16 + c;
        const int cb = (kb * 64 + g * 16) ^ ((row & 7) << 4);
        av[m] = *(const short8*)((const char*)As + row * 128 + cb);
      }
#pragma unroll
      for (int n = 0; n < 4; n++) {
        const int row = wc * 64 + n * 16 + c;
        const int cb = (kb * 64 + g * 16) ^ ((row & 7) << 4);
        bv[n] = *(const short8*)((const char*)Bs + row * 128 + cb);
      }
#pragma unroll
      for (int m = 0; m < 4; m++)
#pragma unroll
        for (int n = 0; n < 4; n++)
          acc[m][n] = __builtin_amdgcn_mfma_f32_16x16x32_bf16(av[m], bv[n], acc[m][n], 0, 0, 0);
    }
    __syncthreads();
  }

#pragma unroll
  for (int m = 0; m < 4; m++) {
    const int row0 = rowbase + wr * 64 + m * 16 + g * 4;
#pragma unroll
    for (int n = 0; n < 4; n++) {
      const int col = colbase + wc * 64 + n * 16 + c;
      const float bb = bias[col];
#pragma unroll
      for (int r = 0; r < 4; r++) {
        float v = acc[m][n][r] + bb;
        const size_t idx = (size_t)(row0 + r) * N + col;
        if (EPI == 1) {
          v = gelu_fast(v);
          ((unsigned short*)Cout)[idx] = f2bf(v);
        } else if (EPI == 2) {
          ((float*)Cout)[idx] = v;
        } else if (EPI == 3) {
          v = (col < 1024) ? v * 0.18033688f : v;  // fold (1/sqrt(64))*log2(e) into Q
          ((unsigned short*)Cout)[idx] = f2bf(v);
        } else {
          ((unsigned short*)Cout)[idx] = f2bf(v);
        }
      }
    }
  }
}

// ---------------- prep: rmsnorm1 + all four weight transposes in ONE launch ----------------
// R22: the five prologue kernels are mutually independent (x vs weights); merging removes
// 4 launch overheads and lets the small grids co-schedule. Block-granular dispatch:
// blk < 8192 -> rmsnorm row; else wtrans tile (ranges: qkv 768, o 256, ff1 1024, ff2 1024).
__global__ __launch_bounds__(256)
void prep(const float* __restrict__ x, const float* __restrict__ n1,
          unsigned short* __restrict__ xn,
          const float* __restrict__ Wq, unsigned short* __restrict__ Wtq,
          const float* __restrict__ Wo, unsigned short* __restrict__ Wto,
          const float* __restrict__ W1, unsigned short* __restrict__ Wt1,
          const float* __restrict__ W2, unsigned short* __restrict__ Wt2) {
  __shared__ unsigned short tile[64][72];
  __shared__ float red[4];
  const int t = threadIdx.x;
  int blk = blockIdx.x;

  if (blk < 8192) {
    // ---- RMSNorm row (fp32 -> bf16) ----
    const float4 v = ((const float4*)(x + (size_t)blk * 1024))[t];
    float ss = v.x * v.x + v.y * v.y + v.z * v.z + v.w * v.w;
#pragma unroll
    for (int d = 1; d < 64; d <<= 1) ss += __shfl_xor(ss, d);
    if ((t & 63) == 0) red[t >> 6] = ss;
    __syncthreads();
    const float tot = red[0] + red[1] + red[2] + red[3];
    const float r = rsqrtf(tot * (1.0f / 1024.0f) + 1e-6f);
    const float4 wv = ((const float4*)n1)[t];
    ushort4 o;
    o.x = f2bf(v.x * r * wv.x);
    o.y = f2bf(v.y * r * wv.y);
    o.z = f2bf(v.z * r * wv.z);
    o.w = f2bf(v.w * r * wv.w);
    *((ushort4*)(xn + (size_t)blk * 1024 + t * 4)) = o;
    return;
  }

  // ---- weight transpose tile: W fp32 [K][N] -> Wt bf16 [N][K] ----
  blk -= 8192;
  const float* W;
  unsigned short* Wt;
  int K, N, nx;
  if (blk < 768)        { W = Wq; Wt = Wtq; K = 1024; N = 3072; nx = 48; }
  else if (blk < 1024)  { blk -= 768;  W = Wo; Wt = Wto; K = 1024; N = 1024; nx = 16; }
  else if (blk < 2048)  { blk -= 1024; W = W1; Wt = Wt1; K = 1024; N = 4096; nx = 64; }
  else                  { blk -= 2048; W = W2; Wt = Wt2; K = 4096; N = 1024; nx = 16; }
  const int n0 = (blk % nx) * 64, k0 = (blk / nx) * 64;
  {
    const int kl = t >> 2, nl0 = (t & 3) * 16;
    const float4* src = (const float4*)(W + (size_t)(k0 + kl) * N + n0 + nl0);
#pragma unroll
    for (int i = 0; i < 4; i++) {
      float4 v = src[i];
      tile[kl][nl0 + i * 4 + 0] = f2bf(v.x);
      tile[kl][nl0 + i * 4 + 1] = f2bf(v.y);
      tile[kl][nl0 + i * 4 + 2] = f2bf(v.z);
      tile[kl][nl0 + i * 4 + 3] = f2bf(v.w);
    }
  }
  __syncthreads();
  {
    const int nl = t >> 2, kl0 = (t & 3) * 16;
    unsigned short* dst = Wt + (size_t)(n0 + nl) * K + k0 + kl0;
    short8 a, b2;
#pragma unroll
    for (int j = 0; j < 8; j++) {
      a[j]  = (short)tile[kl0 + j][nl];
      b2[j] = (short)tile[kl0 + 8 + j][nl];
    }
    *(short8*)dst = a;
    *(short8*)(dst + 8) = b2;
  }
}

// ---------------- V transpose: qkv V-part [b][s][h][dh] -> Vt [b*h][dh][s] ----------------
__global__ __launch_bounds__(256)
void vtrans(const unsigned short* __restrict__ qkv, unsigned short* __restrict__ Vt) {
  __shared__ unsigned short tile[64][72];
  const int blk = blockIdx.x;
  const int st = blk & 31, bh = blk >> 5;
  const int b = bh >> 4, h = bh & 15;
  const int s0 = st * 64;
  const int t = threadIdx.x;
  {
    const int sl = t >> 2, d0 = (t & 3) * 16;
    const unsigned short* src = qkv + (size_t)(b * SEQ + s0 + sl) * 3072 + 2048 + h * 64 + d0;
    short8 v0 = *(const short8*)src;
    short8 v1 = *(const short8*)(src + 8);
#pragma unroll
    for (int j = 0; j < 8; j++) {
      tile[sl][d0 + j] = (unsigned short)v0[j];
      tile[sl][d0 + 8 + j] = (unsigned short)v1[j];
    }
  }
  __syncthreads();
  {
    const int dl = t >> 2, sl0 = (t & 3) * 16;
    unsigned short* dst = Vt + ((size_t)bh * 64 + dl) * SEQ + s0 + sl0;
    short8 a, b2;
#pragma unroll
    for (int j = 0; j < 8; j++) {
      a[j]  = (short)tile[sl0 + j][dl];
      b2[j] = (short)tile[sl0 + 8 + j][dl];
    }
    *(short8*)dst = a;
    *(short8*)(dst + 8) = b2;
  }
}

// ---------------- RMSNorm: bf16 in -> bf16 out (R21: Wo stores bf16) ----------------
__global__ __launch_bounds__(256)
void rmsnorm_bf16_bf16(const unsigned short* __restrict__ x, const float* __restrict__ w,
                       unsigned short* __restrict__ out) {
  __shared__ float red[4];
  const int row = blockIdx.x, t = threadIdx.x;
  const ushort4 v = ((const ushort4*)(x + (size_t)row * 1024))[t];
  const float f0 = bf2f(v.x), f1 = bf2f(v.y), f2 = bf2f(v.z), f3 = bf2f(v.w);
  float ss = f0 * f0 + f1 * f1 + f2 * f2 + f3 * f3;
#pragma unroll
  for (int d = 1; d < 64; d <<= 1) ss += __shfl_xor(ss, d);
  if ((t & 63) == 0) red[t >> 6] = ss;
  __syncthreads();
  const float tot = red[0] + red[1] + red[2] + red[3];
  const float r = rsqrtf(tot * (1.0f / 1024.0f) + 1e-6f);
  const float4 wv = ((const float4*)w)[t];
  ushort4 o;
  o.x = f2bf(f0 * r * wv.x);
  o.y = f2bf(f1 * r * wv.y);
  o.z = f2bf(f2 * r * wv.z);
  o.w = f2bf(f3 * r * wv.w);
  *((ushort4*)(out + (size_t)row * 1024 + t * 4)) = o;
}

// ---------------- flash attention: 8 waves x 32 q-rows, kb2-split + s_setprio (T5) --------
// R12/R16/R18 winner, unchanged.
__global__ __launch_bounds__(512, 4)
void attn(const unsigned short* __restrict__ qkv, const unsigned short* __restrict__ Vt,
          unsigned short* __restrict__ ctx) {
  __shared__ alignas(16) unsigned short Ks[2][64 * 64];
  __shared__ alignas(16) unsigned short Vs[2][64 * 64];
  __shared__ alignas(16) unsigned short Plds[8][32 * 72];
  const int tid = threadIdx.x, lane = tid & 63, wid = tid >> 6;
  const int qb = blockIdx.x & 7, bh = blockIdx.x >> 3;
  const int b = bh >> 4, h = bh & 15;
  const int g = lane >> 4, c = lane & 15;
  const int qrow0 = qb * 256 + wid * 32;

  const unsigned short* Kb = qkv + (size_t)b * SEQ * 3072 + 1024 + h * 64;
  const unsigned short* Vb = Vt + (size_t)bh * 64 * SEQ;

  const int srow = lane >> 3;
  const int swz = (((lane & 7) ^ srow) << 3);

  short8 bq[2][2];
#pragma unroll
  for (int m = 0; m < 2; m++)
#pragma unroll
    for (int kb = 0; kb < 2; kb++) {
      const int sq = qrow0 + m * 16 + c;
      bq[m][kb] = *(const short8*)(qkv + (size_t)(b * SEQ + sq) * 3072 + h * 64 + kb * 32 + g * 8);
    }

  short8 ones;
#pragma unroll
  for (int j = 0; j < 8; j++) ones[j] = (short)0x3F80;

  f32x4 o[2][4];
  f32x4 lacc[2];
#pragma unroll
  for (int m = 0; m < 2; m++) {
#pragma unroll
    for (int nc = 0; nc < 4; nc++) o[m][nc] = f32x4{0.f, 0.f, 0.f, 0.f};
    lacc[m] = f32x4{0.f, 0.f, 0.f, 0.f};
  }

  unsigned short* pw = &Plds[wid][0];

  async_ld16(Kb + (size_t)(wid * 8 + srow) * 3072 + swz, &Ks[0][wid * 512]);
  async_ld16(Vb + (size_t)(wid * 8 + srow) * 2048 + swz, &Vs[0][wid * 512]);
  __syncthreads();

  for (int tt = 0; tt < SEQ / 128; ++tt) {
#pragma unroll
    for (int half = 0; half < 2; ++half) {
      const int t = tt * 2 + half;                  // buf == half (compile-time)
      const char* ksb = (const char*)Ks + half * 8192;
      const char* vsb = (const char*)Vs + half * 8192;
      if (t + 1 < SEQ / 64) {
        const int kt2 = (t + 1) * 64;
        async_ld16(Kb + (size_t)(kt2 + wid * 8 + srow) * 3072 + swz, &Ks[half ^ 1][wid * 512]);
        async_ld16(Vb + (size_t)(wid * 8 + srow) * 2048 + kt2 + swz, &Vs[half ^ 1][wid * 512]);
      }

      // QK: sacc[m][n] reg r = (pre-scaled) S^T[k = n*16+g*4+r][q = m*16+c]
      f32x4 sacc[2][4];
#pragma unroll
      for (int m = 0; m < 2; m++)
#pragma unroll
        for (int n = 0; n < 4; n++) sacc[m][n] = f32x4{0.f, 0.f, 0.f, 0.f};
#pragma unroll
      for (int kb = 0; kb < 2; ++kb) {
        short8 ak[4];
#pragma unroll
        for (int n = 0; n < 4; n++)
          ak[n] = *(const short8*)(ksb + (n * 16 + c) * 128 +
                                   ((kb * 64 + g * 16) ^ ((c & 7) << 4)));
        __builtin_amdgcn_s_setprio(1);
#pragma unroll
        for (int m = 0; m < 2; m++)
#pragma unroll
          for (int n = 0; n < 4; n++)
            sacc[m][n] = __builtin_amdgcn_mfma_f32_16x16x32_bf16(ak[n], bq[m][kb], sacc[m][n], 0, 0, 0);
        __builtin_amdgcn_s_setprio(0);
      }

      // per 32-k half: exp+pack (n = 2*kb2, 2*kb2+1) -> pa -> PV half; PV MFMA of half 0
      // overlaps the exp chain of half 1.
#pragma unroll
      for (int kb2 = 0; kb2 < 2; ++kb2) {
#pragma unroll
        for (int m = 0; m < 2; m++) {
          char* rowp = (char*)pw + (m * 16 + c) * 144;
#pragma unroll
          for (int nn = 0; nn < 2; nn++) {
            const int n = kb2 * 2 + nn;
            const float p0 = __builtin_amdgcn_exp2f(sacc[m][n][0]);
            const float p1 = __builtin_amdgcn_exp2f(sacc[m][n][1]);
            const float p2 = __builtin_amdgcn_exp2f(sacc[m][n][2]);
            const float p3 = __builtin_amdgcn_exp2f(sacc[m][n][3]);
            *(unsigned*)(rowp + (n * 16 + g * 4) * 2)     = pack_bf16x2(p0, p1);
            *(unsigned*)(rowp + (n * 16 + g * 4) * 2 + 4) = pack_bf16x2(p2, p3);
          }
        }
        short8 pa[2];
#pragma unroll
        for (int m = 0; m < 2; m++)
          pa[m] = *(const short8*)((const char*)pw + (m * 16 + c) * 144 + kb2 * 64 + g * 16);
        __builtin_amdgcn_s_setprio(1);
#pragma unroll
        for (int nc = 0; nc < 4; nc++) {
          const short8 vb = *(const short8*)(vsb + (nc * 16 + c) * 128 +
                                             ((kb2 * 64 + g * 16) ^ ((c & 7) << 4)));
#pragma unroll
          for (int m = 0; m < 2; m++)
            o[m][nc] = __builtin_amdgcn_mfma_f32_16x16x32_bf16(pa[m], vb, o[m][nc], 0, 0, 0);
        }
#pragma unroll
        for (int m = 0; m < 2; m++)
          lacc[m] = __builtin_amdgcn_mfma_f32_16x16x32_bf16(pa[m], ones, lacc[m], 0, 0, 0);
        __builtin_amdgcn_s_setprio(0);
      }
      __syncthreads();
    }
  }

  // epilogue: lacc[m][r] = l[q = m*16+g*4+r] — same row mapping as o[m][nc][r]; no shuffles
#pragma unroll
  for (int m = 0; m < 2; m++)
#pragma unroll
    for (int r = 0; r < 4; r++) {
      const float linv = 1.0f / lacc[m][r];
      const int sq = qrow0 + m * 16 + g * 4 + r;
#pragma unroll
      for (int nc = 0; nc < 4; nc++) {
        const int d = h * 64 + nc * 16 + c;
        ctx[(size_t)(b * SEQ + sq) * 1024 + d] = f2bf(o[m][nc][r] * linv);
      }
    }
}

extern "C" void kernel_launch(void* const* d_in, const int* in_sizes, int n_in,
                              void* d_out, int out_size, void* d_ws, size_t ws_size,
                              hipStream_t stream) {
  const float* x     = (const float*)d_in[0];
  const float* W_qkv = (const float*)d_in[1];
  const float* b_qkv = (const float*)d_in[2];
  const float* W_o   = (const float*)d_in[3];
  const float* b_o   = (const float*)d_in[4];
  const float* W_ff1 = (const float*)d_in[5];
  const float* b_ff1 = (const float*)d_in[6];
  const float* W_ff2 = (const float*)d_in[7];
  const float* b_ff2 = (const float*)d_in[8];
  const float* n1    = (const float*)d_in[9];
  const float* n2    = (const float*)d_in[10];
  float* out = (float*)d_out;

  char* p = (char*)d_ws;
  unsigned short* Wt_qkv = (unsigned short*)p; p += (size_t)3072 * 1024 * 2;
  unsigned short* Wt_o   = (unsigned short*)p; p += (size_t)1024 * 1024 * 2;
  unsigned short* Wt_ff1 = (unsigned short*)p; p += (size_t)4096 * 1024 * 2;
  unsigned short* Wt_ff2 = (unsigned short*)p; p += (size_t)1024 * 4096 * 2;
  unsigned short* xn  = (unsigned short*)p; p += (size_t)8192 * 1024 * 2;  // reused as ctx
  unsigned short* qkv = (unsigned short*)p; p += (size_t)8192 * 3072 * 2;  // reused as attn_out(bf16)
  unsigned short* Vt  = (unsigned short*)p; p += (size_t)8192 * 1024 * 2;  // reused as yn
  unsigned short* h   = (unsigned short*)p; p += (size_t)8192 * 4096 * 2;

  unsigned short* ctxb = xn;
  unsigned short* attn_out = qkv;   // bf16 (R21)
  unsigned short* yn = Vt;

  // R22: rmsnorm1 + 4x wtrans in one launch (8192 + 3072 blocks)
  prep<<<11264, 256, 0, stream>>>(x, n1, xn, W_qkv, Wt_qkv, W_o, Wt_o,
                                  W_ff1, Wt_ff1, W_ff2, Wt_ff2);
  gemm_bf16<3><<<24 * 64, 256, 0, stream>>>(xn, Wt_qkv, b_qkv, (void*)qkv, 8192, 3072, 1024);
  vtrans<<<2048, 256, 0, stream>>>(qkv, Vt);
  attn<<<512, 512, 0, stream>>>(qkv, Vt, ctxb);
  gemm_bf16<0><<<8 * 64, 256, 0, stream>>>(ctxb, Wt_o, b_o, (void*)attn_out, 8192, 1024, 1024);
  rmsnorm_bf16_bf16<<<8192, 256, 0, stream>>>(attn_out, n2, yn);
  gemm_bf16<1><<<32 * 64, 256, 0, stream>>>(yn, Wt_ff1, b_ff1, (void*)h, 8192, 4096, 1024);
  gemm_bf16<2><<<8 * 64, 256, 0, stream>>>(h, Wt_ff2, b_ff2, (void*)out, 8192, 1024, 4096);
}

// Round 23
// 365.339 us; speedup vs baseline: 1.1489x; 1.0200x over previous
//
#include <hip/hip_runtime.h>
#include <hip/hip_bf16.h>

#define SEQ 2048

typedef __attribute__((ext_vector_type(8))) short short8;
typedef __attribute__((ext_vector_type(4))) float f32x4;

__device__ __forceinline__ unsigned short f2bf(float f) {
  unsigned u = __float_as_uint(f);
  u += 0x7fffu + ((u >> 16) & 1u);
  return (unsigned short)(u >> 16);
}

__device__ __forceinline__ float bf2f(unsigned short v) {
  return __uint_as_float(((unsigned)v) << 16);
}

// Pack two f32 -> bf16x2 via the COMPILER-VISIBLE HIP conversion (no inline asm).
// R13-R16 lesson: v_exp_f32 is a TRANS op with a result-use wait-state; the hazard
// recognizer does NOT pad when the consumer is an opaque inline-asm block.
__device__ __forceinline__ unsigned pack_bf16x2(float lo, float hi) {
  __hip_bfloat162 h = __float22bfloat162_rn(float2{lo, hi});
  unsigned r;
  __builtin_memcpy(&r, &h, 4);
  return r;
}

// tanh-form GELU: x * sigmoid(1.5957691*x*(1+0.044715*x^2)). Max |err| vs erf-GELU ~3e-4.
__device__ __forceinline__ float gelu_fast(float x) {
  const float u = 1.5957691f * x * __builtin_fmaf(0.044715f, x * x, 1.0f);
  const float e = __builtin_amdgcn_exp2f(-1.4426950408889634f * u);  // exp(-u)
  return x * __builtin_amdgcn_rcpf(1.0f + e);
}

__device__ __forceinline__ void async_ld16(const unsigned short* g, unsigned short* l) {
  __builtin_amdgcn_global_load_lds((const __attribute__((address_space(1))) unsigned int*)g,
                                   (__attribute__((address_space(3))) unsigned int*)l, 16, 0, 0);
}

// ---------------- 128x128 GEMM (verified m97-class) + T1 supertile XCD swizzle ------------
// EPI 0: bf16 store; EPI 1: gelu+bf16; EPI 2: fp32; EPI 3: QKV epilogue — Q cols scaled by
// log2(e)/8, V cols (>=2048) written DIRECTLY to Vt[bh*64+dh][s] (R23: fuses vtrans; the
// 4 r-values are contiguous in s -> one ushort4 store; qkv's V third becomes dead).
// R20: 8x4 supertile decode inside XCD-chunked remap — per-XCD window 3MB < 4MB L2.
template<int EPI>
__global__ __launch_bounds__(256)
void gemm_bf16(const unsigned short* __restrict__ A,
               const unsigned short* __restrict__ Bt,
               const float* __restrict__ bias,
               void* __restrict__ Cout,
               unsigned short* __restrict__ Vt,
               int M, int N, int K) {
  __shared__ alignas(16) unsigned short As[128 * 64];
  __shared__ alignas(16) unsigned short Bs[128 * 64];
  const int tid = threadIdx.x;
  const int lane = tid & 63;
  const int wid = tid >> 6;
  const int wr = wid >> 1, wc = wid & 1;

  // T1: XCD-chunked bijective remap, supertile decode.
  const int nwg = gridDim.x;
  const int lin = (blockIdx.x & 7) * (nwg >> 3) + (blockIdx.x >> 3);
  const int nstx = N >> 9;              // (N/128)/4 supertile columns
  const int st = lin >> 5;              // 32 blocks per 8x4 supertile
  const int i = lin & 31;
  const int byg = st / nstx;            // row-group-major: A-rows shared per XCD
  const int bxg = st - byg * nstx;
  const int rowbase = (byg * 8 + (i >> 2)) * 128;
  const int colbase = (bxg * 4 + (i & 3)) * 128;
  const int g = lane >> 4, c = lane & 15;

  f32x4 acc[4][4];
#pragma unroll
  for (int m = 0; m < 4; m++)
#pragma unroll
    for (int n = 0; n < 4; n++) acc[m][n] = f32x4{0.f, 0.f, 0.f, 0.f};

  const int lrow = lane >> 3;
  const int swzel = (((lane & 7) ^ lrow) << 3);
  const unsigned short* gA = A + (size_t)(rowbase + wid * 32 + lrow) * K + swzel;
  const unsigned short* gB = Bt + (size_t)(colbase + wid * 32 + lrow) * K + swzel;
  unsigned short* lA = As + wid * 2048;
  unsigned short* lB = Bs + wid * 2048;

  for (int kt = 0; kt < K; kt += 64) {
#pragma unroll
    for (int i2 = 0; i2 < 4; i2++) async_ld16(gA + kt + (size_t)i2 * 8 * K, lA + i2 * 512);
#pragma unroll
    for (int i2 = 0; i2 < 4; i2++) async_ld16(gB + kt + (size_t)i2 * 8 * K, lB + i2 * 512);
    __syncthreads();
#pragma unroll
    for (int kb = 0; kb < 2; ++kb) {
      short8 av[4], bv[4];
#pragma unroll
      for (int m = 0; m < 4; m++) {
        const int row = wr * 64 + m * 16 + c;
        const int cb = (kb * 64 + g * 16) ^ ((row & 7) << 4);
        av[m] = *(const short8*)((const char*)As + row * 128 + cb);
      }
#pragma unroll
      for (int n = 0; n < 4; n++) {
        const int row = wc * 64 + n * 16 + c;
        const int cb = (kb * 64 + g * 16) ^ ((row & 7) << 4);
        bv[n] = *(const short8*)((const char*)Bs + row * 128 + cb);
      }
#pragma unroll
      for (int m = 0; m < 4; m++)
#pragma unroll
        for (int n = 0; n < 4; n++)
          acc[m][n] = __builtin_amdgcn_mfma_f32_16x16x32_bf16(av[m], bv[n], acc[m][n], 0, 0, 0);
    }
    __syncthreads();
  }

#pragma unroll
  for (int m = 0; m < 4; m++) {
    const int row0 = rowbase + wr * 64 + m * 16 + g * 4;
#pragma unroll
    for (int n = 0; n < 4; n++) {
      const int col = colbase + wc * 64 + n * 16 + c;
      const float bb = bias[col];
      if (EPI == 3 && col >= 2048) {
        // V column: write straight to Vt[(b*16+h)*64+dh][s] — 4 r-values contiguous in s.
        const int vcol = col - 2048;
        const int b_ = row0 >> 11;
        const int s0 = row0 & 2047;
        ushort4 vv;
        vv.x = f2bf(acc[m][n][0] + bb);
        vv.y = f2bf(acc[m][n][1] + bb);
        vv.z = f2bf(acc[m][n][2] + bb);
        vv.w = f2bf(acc[m][n][3] + bb);
        *(ushort4*)(Vt + ((size_t)((b_ << 4) + (vcol >> 6)) * 64 + (vcol & 63)) * SEQ + s0) = vv;
        continue;
      }
#pragma unroll
      for (int r = 0; r < 4; r++) {
        float v = acc[m][n][r] + bb;
        const size_t idx = (size_t)(row0 + r) * N + col;
        if (EPI == 1) {
          v = gelu_fast(v);
          ((unsigned short*)Cout)[idx] = f2bf(v);
        } else if (EPI == 2) {
          ((float*)Cout)[idx] = v;
        } else if (EPI == 3) {
          v = (col < 1024) ? v * 0.18033688f : v;  // fold (1/sqrt(64))*log2(e) into Q
          ((unsigned short*)Cout)[idx] = f2bf(v);
        } else {
          ((unsigned short*)Cout)[idx] = f2bf(v);
        }
      }
    }
  }
}

// ---------------- prep: rmsnorm1 + all four weight transposes in ONE launch ----------------
// R22: the five prologue kernels are mutually independent; merging removes 4 launch
// overheads and co-schedules the small grids (-6µs).
__global__ __launch_bounds__(256)
void prep(const float* __restrict__ x, const float* __restrict__ n1,
          unsigned short* __restrict__ xn,
          const float* __restrict__ Wq, unsigned short* __restrict__ Wtq,
          const float* __restrict__ Wo, unsigned short* __restrict__ Wto,
          const float* __restrict__ W1, unsigned short* __restrict__ Wt1,
          const float* __restrict__ W2, unsigned short* __restrict__ Wt2) {
  __shared__ unsigned short tile[64][72];
  __shared__ float red[4];
  const int t = threadIdx.x;
  int blk = blockIdx.x;

  if (blk < 8192) {
    // ---- RMSNorm row (fp32 -> bf16) ----
    const float4 v = ((const float4*)(x + (size_t)blk * 1024))[t];
    float ss = v.x * v.x + v.y * v.y + v.z * v.z + v.w * v.w;
#pragma unroll
    for (int d = 1; d < 64; d <<= 1) ss += __shfl_xor(ss, d);
    if ((t & 63) == 0) red[t >> 6] = ss;
    __syncthreads();
    const float tot = red[0] + red[1] + red[2] + red[3];
    const float r = rsqrtf(tot * (1.0f / 1024.0f) + 1e-6f);
    const float4 wv = ((const float4*)n1)[t];
    ushort4 o;
    o.x = f2bf(v.x * r * wv.x);
    o.y = f2bf(v.y * r * wv.y);
    o.z = f2bf(v.z * r * wv.z);
    o.w = f2bf(v.w * r * wv.w);
    *((ushort4*)(xn + (size_t)blk * 1024 + t * 4)) = o;
    return;
  }

  // ---- weight transpose tile: W fp32 [K][N] -> Wt bf16 [N][K] ----
  blk -= 8192;
  const float* W;
  unsigned short* Wt;
  int K, N, nx;
  if (blk < 768)        { W = Wq; Wt = Wtq; K = 1024; N = 3072; nx = 48; }
  else if (blk < 1024)  { blk -= 768;  W = Wo; Wt = Wto; K = 1024; N = 1024; nx = 16; }
  else if (blk < 2048)  { blk -= 1024; W = W1; Wt = Wt1; K = 1024; N = 4096; nx = 64; }
  else                  { blk -= 2048; W = W2; Wt = Wt2; K = 4096; N = 1024; nx = 16; }
  const int n0 = (blk % nx) * 64, k0 = (blk / nx) * 64;
  {
    const int kl = t >> 2, nl0 = (t & 3) * 16;
    const float4* src = (const float4*)(W + (size_t)(k0 + kl) * N + n0 + nl0);
#pragma unroll
    for (int i = 0; i < 4; i++) {
      float4 v = src[i];
      tile[kl][nl0 + i * 4 + 0] = f2bf(v.x);
      tile[kl][nl0 + i * 4 + 1] = f2bf(v.y);
      tile[kl][nl0 + i * 4 + 2] = f2bf(v.z);
      tile[kl][nl0 + i * 4 + 3] = f2bf(v.w);
    }
  }
  __syncthreads();
  {
    const int nl = t >> 2, kl0 = (t & 3) * 16;
    unsigned short* dst = Wt + (size_t)(n0 + nl) * K + k0 + kl0;
    short8 a, b2;
#pragma unroll
    for (int j = 0; j < 8; j++) {
      a[j]  = (short)tile[kl0 + j][nl];
      b2[j] = (short)tile[kl0 + 8 + j][nl];
    }
    *(short8*)dst = a;
    *(short8*)(dst + 8) = b2;
  }
}

// ---------------- RMSNorm: bf16 in -> bf16 out (R21: Wo stores bf16) ----------------
__global__ __launch_bounds__(256)
void rmsnorm_bf16_bf16(const unsigned short* __restrict__ x, const float* __restrict__ w,
                       unsigned short* __restrict__ out) {
  __shared__ float red[4];
  const int row = blockIdx.x, t = threadIdx.x;
  const ushort4 v = ((const ushort4*)(x + (size_t)row * 1024))[t];
  const float f0 = bf2f(v.x), f1 = bf2f(v.y), f2 = bf2f(v.z), f3 = bf2f(v.w);
  float ss = f0 * f0 + f1 * f1 + f2 * f2 + f3 * f3;
#pragma unroll
  for (int d = 1; d < 64; d <<= 1) ss += __shfl_xor(ss, d);
  if ((t & 63) == 0) red[t >> 6] = ss;
  __syncthreads();
  const float tot = red[0] + red[1] + red[2] + red[3];
  const float r = rsqrtf(tot * (1.0f / 1024.0f) + 1e-6f);
  const float4 wv = ((const float4*)w)[t];
  ushort4 o;
  o.x = f2bf(f0 * r * wv.x);
  o.y = f2bf(f1 * r * wv.y);
  o.z = f2bf(f2 * r * wv.z);
  o.w = f2bf(f3 * r * wv.w);
  *((ushort4*)(out + (size_t)row * 1024 + t * 4)) = o;
}

// ---------------- flash attention: 8 waves x 32 q-rows, kb2-split + s_setprio (T5) --------
// R12/R16/R18 winner, unchanged.
__global__ __launch_bounds__(512, 4)
void attn(const unsigned short* __restrict__ qkv, const unsigned short* __restrict__ Vt,
          unsigned short* __restrict__ ctx) {
  __shared__ alignas(16) unsigned short Ks[2][64 * 64];
  __shared__ alignas(16) unsigned short Vs[2][64 * 64];
  __shared__ alignas(16) unsigned short Plds[8][32 * 72];
  const int tid = threadIdx.x, lane = tid & 63, wid = tid >> 6;
  const int qb = blockIdx.x & 7, bh = blockIdx.x >> 3;
  const int b = bh >> 4, h = bh & 15;
  const int g = lane >> 4, c = lane & 15;
  const int qrow0 = qb * 256 + wid * 32;

  const unsigned short* Kb = qkv + (size_t)b * SEQ * 3072 + 1024 + h * 64;
  const unsigned short* Vb = Vt + (size_t)bh * 64 * SEQ;

  const int srow = lane >> 3;
  const int swz = (((lane & 7) ^ srow) << 3);

  short8 bq[2][2];
#pragma unroll
  for (int m = 0; m < 2; m++)
#pragma unroll
    for (int kb = 0; kb < 2; kb++) {
      const int sq = qrow0 + m * 16 + c;
      bq[m][kb] = *(const short8*)(qkv + (size_t)(b * SEQ + sq) * 3072 + h * 64 + kb * 32 + g * 8);
    }

  short8 ones;
#pragma unroll
  for (int j = 0; j < 8; j++) ones[j] = (short)0x3F80;

  f32x4 o[2][4];
  f32x4 lacc[2];
#pragma unroll
  for (int m = 0; m < 2; m++) {
#pragma unroll
    for (int nc = 0; nc < 4; nc++) o[m][nc] = f32x4{0.f, 0.f, 0.f, 0.f};
    lacc[m] = f32x4{0.f, 0.f, 0.f, 0.f};
  }

  unsigned short* pw = &Plds[wid][0];

  async_ld16(Kb + (size_t)(wid * 8 + srow) * 3072 + swz, &Ks[0][wid * 512]);
  async_ld16(Vb + (size_t)(wid * 8 + srow) * 2048 + swz, &Vs[0][wid * 512]);
  __syncthreads();

  for (int tt = 0; tt < SEQ / 128; ++tt) {
#pragma unroll
    for (int half = 0; half < 2; ++half) {
      const int t = tt * 2 + half;                  // buf == half (compile-time)
      const char* ksb = (const char*)Ks + half * 8192;
      const char* vsb = (const char*)Vs + half * 8192;
      if (t + 1 < SEQ / 64) {
        const int kt2 = (t + 1) * 64;
        async_ld16(Kb + (size_t)(kt2 + wid * 8 + srow) * 3072 + swz, &Ks[half ^ 1][wid * 512]);
        async_ld16(Vb + (size_t)(wid * 8 + srow) * 2048 + kt2 + swz, &Vs[half ^ 1][wid * 512]);
      }

      // QK: sacc[m][n] reg r = (pre-scaled) S^T[k = n*16+g*4+r][q = m*16+c]
      f32x4 sacc[2][4];
#pragma unroll
      for (int m = 0; m < 2; m++)
#pragma unroll
        for (int n = 0; n < 4; n++) sacc[m][n] = f32x4{0.f, 0.f, 0.f, 0.f};
#pragma unroll
      for (int kb = 0; kb < 2; ++kb) {
        short8 ak[4];
#pragma unroll
        for (int n = 0; n < 4; n++)
          ak[n] = *(const short8*)(ksb + (n * 16 + c) * 128 +
                                   ((kb * 64 + g * 16) ^ ((c & 7) << 4)));
        __builtin_amdgcn_s_setprio(1);
#pragma unroll
        for (int m = 0; m < 2; m++)
#pragma unroll
          for (int n = 0; n < 4; n++)
            sacc[m][n] = __builtin_amdgcn_mfma_f32_16x16x32_bf16(ak[n], bq[m][kb], sacc[m][n], 0, 0, 0);
        __builtin_amdgcn_s_setprio(0);
      }

      // per 32-k half: exp+pack (n = 2*kb2, 2*kb2+1) -> pa -> PV half; PV MFMA of half 0
      // overlaps the exp chain of half 1.
#pragma unroll
      for (int kb2 = 0; kb2 < 2; ++kb2) {
#pragma unroll
        for (int m = 0; m < 2; m++) {
          char* rowp = (char*)pw + (m * 16 + c) * 144;
#pragma unroll
          for (int nn = 0; nn < 2; nn++) {
            const int n = kb2 * 2 + nn;
            const float p0 = __builtin_amdgcn_exp2f(sacc[m][n][0]);
            const float p1 = __builtin_amdgcn_exp2f(sacc[m][n][1]);
            const float p2 = __builtin_amdgcn_exp2f(sacc[m][n][2]);
            const float p3 = __builtin_amdgcn_exp2f(sacc[m][n][3]);
            *(unsigned*)(rowp + (n * 16 + g * 4) * 2)     = pack_bf16x2(p0, p1);
            *(unsigned*)(rowp + (n * 16 + g * 4) * 2 + 4) = pack_bf16x2(p2, p3);
          }
        }
        short8 pa[2];
#pragma unroll
        for (int m = 0; m < 2; m++)
          pa[m] = *(const short8*)((const char*)pw + (m * 16 + c) * 144 + kb2 * 64 + g * 16);
        __builtin_amdgcn_s_setprio(1);
#pragma unroll
        for (int nc = 0; nc < 4; nc++) {
          const short8 vb = *(const short8*)(vsb + (nc * 16 + c) * 128 +
                                             ((kb2 * 64 + g * 16) ^ ((c & 7) << 4)));
#pragma unroll
          for (int m = 0; m < 2; m++)
            o[m][nc] = __builtin_amdgcn_mfma_f32_16x16x32_bf16(pa[m], vb, o[m][nc], 0, 0, 0);
        }
#pragma unroll
        for (int m = 0; m < 2; m++)
          lacc[m] = __builtin_amdgcn_mfma_f32_16x16x32_bf16(pa[m], ones, lacc[m], 0, 0, 0);
        __builtin_amdgcn_s_setprio(0);
      }
      __syncthreads();
    }
  }

  // epilogue: lacc[m][r] = l[q = m*16+g*4+r] — same row mapping as o[m][nc][r]; no shuffles
#pragma unroll
  for (int m = 0; m < 2; m++)
#pragma unroll
    for (int r = 0; r < 4; r++) {
      const float linv = 1.0f / lacc[m][r];
      const int sq = qrow0 + m * 16 + g * 4 + r;
#pragma unroll
      for (int nc = 0; nc < 4; nc++) {
        const int d = h * 64 + nc * 16 + c;
        ctx[(size_t)(b * SEQ + sq) * 1024 + d] = f2bf(o[m][nc][r] * linv);
      }
    }
}

extern "C" void kernel_launch(void* const* d_in, const int* in_sizes, int n_in,
                              void* d_out, int out_size, void* d_ws, size_t ws_size,
                              hipStream_t stream) {
  const float* x     = (const float*)d_in[0];
  const float* W_qkv = (const float*)d_in[1];
  const float* b_qkv = (const float*)d_in[2];
  const float* W_o   = (const float*)d_in[3];
  const float* b_o   = (const float*)d_in[4];
  const float* W_ff1 = (const float*)d_in[5];
  const float* b_ff1 = (const float*)d_in[6];
  const float* W_ff2 = (const float*)d_in[7];
  const float* b_ff2 = (const float*)d_in[8];
  const float* n1    = (const float*)d_in[9];
  const float* n2    = (const float*)d_in[10];
  float* out = (float*)d_out;

  char* p = (char*)d_ws;
  unsigned short* Wt_qkv = (unsigned short*)p; p += (size_t)3072 * 1024 * 2;
  unsigned short* Wt_o   = (unsigned short*)p; p += (size_t)1024 * 1024 * 2;
  unsigned short* Wt_ff1 = (unsigned short*)p; p += (size_t)4096 * 1024 * 2;
  unsigned short* Wt_ff2 = (unsigned short*)p; p += (size_t)1024 * 4096 * 2;
  unsigned short* xn  = (unsigned short*)p; p += (size_t)8192 * 1024 * 2;  // reused as ctx
  unsigned short* qkv = (unsigned short*)p; p += (size_t)8192 * 3072 * 2;  // reused as attn_out(bf16)
  unsigned short* Vt  = (unsigned short*)p; p += (size_t)8192 * 1024 * 2;  // reused as yn
  unsigned short* h   = (unsigned short*)p; p += (size_t)8192 * 4096 * 2;

  unsigned short* ctxb = xn;
  unsigned short* attn_out = qkv;   // bf16 (R21)
  unsigned short* yn = Vt;

  // R22: rmsnorm1 + 4x wtrans in one launch (8192 + 3072 blocks)
  prep<<<11264, 256, 0, stream>>>(x, n1, xn, W_qkv, Wt_qkv, W_o, Wt_o,
                                  W_ff1, Wt_ff1, W_ff2, Wt_ff2);
  // R23: QKV GEMM writes V directly to Vt (vtrans fused away)
  gemm_bf16<3><<<24 * 64, 256, 0, stream>>>(xn, Wt_qkv, b_qkv, (void*)qkv, Vt, 8192, 3072, 1024);
  attn<<<512, 512, 0, stream>>>(qkv, Vt, ctxb);
  gemm_bf16<0><<<8 * 64, 256, 0, stream>>>(ctxb, Wt_o, b_o, (void*)attn_out, nullptr, 8192, 1024, 1024);
  rmsnorm_bf16_bf16<<<8192, 256, 0, stream>>>(attn_out, n2, yn);
  gemm_bf16<1><<<32 * 64, 256, 0, stream>>>(yn, Wt_ff1, b_ff1, (void*)h, nullptr, 8192, 4096, 1024);
  gemm_bf16<2><<<8 * 64, 256, 0, stream>>>(h, Wt_ff2, b_ff2, (void*)out, nullptr, 8192, 1024, 4096);
}